// Round 7
// baseline (234.728 us; speedup 1.0000x reference)
//
#include <hip/hip_runtime.h>
#include <hip/hip_bf16.h>

#define NN 12288
#define NE 196608
#define HD 128
#define ZD 128
#define NEGV (-1.0e9f)
#define SEG 16

using s8v = __attribute__((ext_vector_type(8))) short;  // 8 bf16 = 4 VGPRs
using f4v = __attribute__((ext_vector_type(4))) float;  // 4 fp32 acc
using i4v = __attribute__((ext_vector_type(4))) int;

__device__ __forceinline__ unsigned short f2bf(float f) {
    return __builtin_bit_cast(unsigned short, __float2bfloat16(f));
}
__device__ __forceinline__ float4 pack8(float4 a, float4 b) {
    unsigned p0 = ((unsigned)f2bf(a.y) << 16) | f2bf(a.x);
    unsigned p1 = ((unsigned)f2bf(a.w) << 16) | f2bf(a.z);
    unsigned p2 = ((unsigned)f2bf(b.y) << 16) | f2bf(b.x);
    unsigned p3 = ((unsigned)f2bf(b.w) << 16) | f2bf(b.z);
    i4v r = (i4v){(int)p0, (int)p1, (int)p2, (int)p3};
    return __builtin_bit_cast(float4, r);
}

// Mega split-grid of INDEPENDENT prep work:
// [0,768): edge in-degree count; [768,816): depth-bucket count (LDS hist ->
// line-padded counters); [816,1264): 7x weight transpose; [1264]: cz1/cz2.
__global__ __launch_bounds__(256) void k_counts_wz(
        const int* __restrict__ edst, const int* __restrict__ ndep,
        const float* __restrict__ W2, const float* __restrict__ Wm1,
        const float* __restrict__ Wm2, const float* __restrict__ Wtm,
        const float* __restrict__ Wsm, const float* __restrict__ Wi1,
        const float* __restrict__ z, const float* __restrict__ bm1,
        const float* __restrict__ bi1,
        int* degi, int* cnt, __hip_bfloat16* __restrict__ wt7,
        float* cz1, float* cz2) {
    __shared__ int lh[64];
    int tid = threadIdx.x;
    int bid = blockIdx.x;
    if (bid < NE / 256) {
        int e = bid * 256 + tid;
        atomicAdd(&degi[edst[e]], 1);
    } else if (bid < NE / 256 + NN / 256) {
        // depth histogram: LDS-aggregate, then 1 global atomic per depth per
        // block onto stride-16 (one-per-cacheline) counters -> no cross-XCD
        // same-line atomic ping-pong.
        if (tid < 64) lh[tid] = 0;
        __syncthreads();
        int v = (bid - NE / 256) * 256 + tid;
        atomicAdd(&lh[ndep[v]], 1);
        __syncthreads();
        if (tid < 64) {
            int c = lh[tid];
            if (c) atomicAdd(&cnt[tid * 16], c);
        }
    } else if (bid < NE / 256 + NN / 256 + 448) {
        int flat = (bid - NE / 256 - NN / 256) * 256 + tid;  // < 7*16384
        int g = flat >> 14;
        int rem = flat & 16383;
        int k = rem >> 7, n = rem & 127;
        const float* src;
        if (g == 0) src = W2;
        else if (g == 1) src = Wm1;
        else if (g == 2) src = Wm2;
        else if (g == 3) src = Wtm;
        else if (g == 4) src = Wsm;
        else if (g == 5) src = Wi1;
        else src = Wi1 + 128 * HD;
        wt7[(g << 14) + n * 128 + k] = __float2bfloat16(src[rem]);
    } else {
        int j = tid & 127;
        const float* W = (tid < 128) ? (Wm1 + HD * HD) : (Wi1 + 2 * HD * HD);
        float A0 = 0.f, A1 = 0.f, A2 = 0.f, A3 = 0.f;
        for (int k = 0; k < ZD; k += 4) {
            A0 = fmaf(z[k],     W[(k    ) * HD + j], A0);
            A1 = fmaf(z[k + 1], W[(k + 1) * HD + j], A1);
            A2 = fmaf(z[k + 2], W[(k + 2) * HD + j], A2);
            A3 = fmaf(z[k + 3], W[(k + 3) * HD + j], A3);
        }
        float r = (A0 + A1) + (A2 + A3);
        if (tid < 128) cz1[j] = r + bm1[j];
        else           cz2[j] = r + bi1[j];
    }
}

// ONE block, 1024 threads: CSR offsets (+cursor), inv = rsqrt(deg+1), agg2
// self term, plus (tid 0) the 64-bucket depth scan -> bofs/dcur.
// v2: LDS-staged, fully coalesced global access.
__global__ __launch_bounds__(1024) void k_prefix(const int* __restrict__ degi,
                                                 const int* __restrict__ cnt,
                                                 const float* __restrict__ x,
                                                 float* inv, float* agg2,
                                                 int* offs, int* cursor,
                                                 int* bofs, int* dcur) {
    __shared__ int ldeg[NN];     // 48 KB: degi, then overwritten by prefix
    __shared__ int part[1024];   // 4 KB
    __shared__ int stot;
    int tid = threadIdx.x;
#pragma unroll
    for (int k = 0; k < 12; ++k)          // coalesced: lane-stride 4B
        ldeg[k * 1024 + tid] = degi[k * 1024 + tid];
    __syncthreads();
    int base = tid * 12;
    int s = 0;
#pragma unroll
    for (int k = 0; k < 12; ++k) s += ldeg[base + k];
    part[tid] = s;
    __syncthreads();
    for (int off = 1; off < 1024; off <<= 1) {
        int v = (tid >= off) ? part[tid - off] : 0;
        __syncthreads();
        part[tid] += v;
        __syncthreads();
    }
    int run = part[tid] - s;  // exclusive base for this thread's 12 elems
#pragma unroll
    for (int k = 0; k < 12; ++k) {        // overwrite LDS with excl prefix
        int d = ldeg[base + k];
        ldeg[base + k] = run;
        run += d;
    }
    if (tid == 1023) stot = run;          // grand total
    __syncthreads();
    int total = stot;
    const float2* X2 = (const float2*)x;
    float2* A2 = (float2*)agg2;
#pragma unroll
    for (int k = 0; k < 12; ++k) {        // coalesced output phase
        int i = k * 1024 + tid;
        int p = ldeg[i];
        int nxt = (i < NN - 1) ? ldeg[i + 1] : total;
        int d = nxt - p;                  // recover degree
        offs[i] = p;
        cursor[i] = p;
        float iv = rsqrtf((float)(d + 1));
        inv[i] = iv;
        float w = iv * iv;
        float2 xv = X2[i];
        float2 av; av.x = xv.x * w; av.y = xv.y * w;
        A2[i] = av;
    }
    if (tid == 0) {
        offs[NN] = total;
        int r = 0;                        // depth-bucket exclusive scan
        for (int d = 0; d < 64; ++d) {
            bofs[d] = r;
            dcur[d * 16] = r;
            r += cnt[d * 16];
        }
        bofs[64] = r;
    }
}

// Split grid: blocks [0,768) bucket edges; [768,816) depth-sort scatter
// (LDS local-rank + one padded global atomic per depth per block).
__global__ __launch_bounds__(256) void k_bucket_scatter(
        const int* __restrict__ esrc, const int* __restrict__ edst,
        const int* __restrict__ ndep, const float* __restrict__ inv,
        int* cursor, int* ebsrc, float* ebw,
        int* dcur, int* sidx, int* sdep, int* prank) {
    __shared__ int lh[64];
    __shared__ int lbase[64];
    int tid = threadIdx.x;
    if (blockIdx.x < NE / 256) {
        int e = blockIdx.x * 256 + tid;
        int u = esrc[e], v = edst[e];
        int pos = atomicAdd(&cursor[v], 1);
        ebsrc[pos] = u;
        ebw[pos] = inv[u] * inv[v];
    } else {
        if (tid < 64) lh[tid] = 0;
        __syncthreads();
        int v = (blockIdx.x - NE / 256) * 256 + tid;
        int d = ndep[v];
        int r = atomicAdd(&lh[d], 1);          // local rank within block
        __syncthreads();
        if (tid < 64) {
            int c = lh[tid];
            if (c) lbase[tid] = atomicAdd(&dcur[tid * 16], c);
        }
        __syncthreads();
        int p = lbase[d] + r;
        sidx[p] = v;
        sdep[p] = d;
        prank[v] = p;
    }
}

// Layer-1 aggregation: 8 lanes per node (v2 — old 48-block version left 208
// CUs idle and naked dependent-load latency; now 384 blocks + shfl reduce).
__global__ __launch_bounds__(256) void k_gather2(const int* __restrict__ offs,
                                                 const int* __restrict__ ebsrc,
                                                 const float* __restrict__ ebw,
                                                 const float* __restrict__ x,
                                                 float* agg2) {
    int t = blockIdx.x * 256 + threadIdx.x;
    int v = t >> 3;
    int sl = t & 7;
    int b = offs[v], e = offs[v + 1];
    const float2* X2 = (const float2*)x;
    float ax = 0.f, ay = 0.f;
    for (int k = b + sl; k < e; k += 8) {
        int u = ebsrc[k];
        float w = ebw[k];
        float2 xv = X2[u];
        ax = fmaf(xv.x, w, ax);
        ay = fmaf(xv.y, w, ay);
    }
#pragma unroll
    for (int m = 1; m < 8; m <<= 1) {   // 8-lane groups are lane-aligned
        ax += __shfl_xor(ax, m, 64);
        ay += __shfl_xor(ay, m, 64);
    }
    if (sl == 0) {
        float2* A2 = (float2*)agg2;
        float2 cur = A2[v];             // self term seeded by k_prefix
        cur.x += ax; cur.y += ay;
        A2[v] = cur;
    }
}

// h1 (bf16) = relu(agg2 @ W1 + b1); seed aggH with layer-2 self-loop term.
__global__ __launch_bounds__(256) void k_lin1(const float* __restrict__ agg2,
                                              const float* __restrict__ W1,
                                              const float* __restrict__ b1,
                                              const float* __restrict__ inv,
                                              unsigned short* h1b, float* aggH) {
    int t = blockIdx.x * 256 + threadIdx.x;
    int v = t >> 7, j = t & 127;
    float hv = fmaxf(fmaf(agg2[2 * v], W1[j],
                     fmaf(agg2[2 * v + 1], W1[HD + j], b1[j])), 0.f);
    h1b[t] = f2bf(hv);
    float iv = inv[v];
    aggH[t] = hv * iv * iv;
}

// Layer-2 aggregation: one WAVE per node, bf16 rows, 4x-unrolled.
__global__ __launch_bounds__(256) void k_gatherH(const int* __restrict__ offs,
                                                 const int* __restrict__ ebsrc,
                                                 const float* __restrict__ ebw,
                                                 const unsigned short* __restrict__ h1b,
                                                 float* aggH) {
    int tid = threadIdx.x;
    int lane = tid & 63;
    int v = blockIdx.x * 4 + (tid >> 6);
    const unsigned* H1 = (const unsigned*)h1b;
    float2* A2 = (float2*)aggH;
    float2 acc = A2[(size_t)v * 64 + lane];
    int b = offs[v], e = offs[v + 1];
    int k = b;
    for (; k + 4 <= e; k += 4) {
        int u0 = ebsrc[k], u1 = ebsrc[k + 1], u2 = ebsrc[k + 2], u3 = ebsrc[k + 3];
        float w0 = ebw[k], w1 = ebw[k + 1], w2 = ebw[k + 2], w3 = ebw[k + 3];
        unsigned hb0 = H1[(size_t)u0 * 64 + lane];
        unsigned hb1 = H1[(size_t)u1 * 64 + lane];
        unsigned hb2 = H1[(size_t)u2 * 64 + lane];
        unsigned hb3 = H1[(size_t)u3 * 64 + lane];
        acc.x = fmaf(__builtin_bit_cast(float, hb0 << 16), w0, acc.x);
        acc.y = fmaf(__builtin_bit_cast(float, hb0 & 0xFFFF0000u), w0, acc.y);
        acc.x = fmaf(__builtin_bit_cast(float, hb1 << 16), w1, acc.x);
        acc.y = fmaf(__builtin_bit_cast(float, hb1 & 0xFFFF0000u), w1, acc.y);
        acc.x = fmaf(__builtin_bit_cast(float, hb2 << 16), w2, acc.x);
        acc.y = fmaf(__builtin_bit_cast(float, hb2 & 0xFFFF0000u), w2, acc.y);
        acc.x = fmaf(__builtin_bit_cast(float, hb3 << 16), w3, acc.x);
        acc.y = fmaf(__builtin_bit_cast(float, hb3 & 0xFFFF0000u), w3, acc.y);
    }
    for (; k < e; ++k) {
        int u = ebsrc[k];
        float w = ebw[k];
        unsigned hb = H1[(size_t)u * 64 + lane];
        acc.x = fmaf(__builtin_bit_cast(float, hb << 16), w, acc.x);
        acc.y = fmaf(__builtin_bit_cast(float, hb & 0xFFFF0000u), w, acc.y);
    }
    A2[(size_t)v * 64 + lane] = acc;
}

// ===== Fused 7-GEMM MLP chain on MFMA (r10-proven; ht/hs scatter to sorted
// row positions via prank) =====
#define AFRAGS(BUF) \
    s8v a0_ = __builtin_bit_cast(s8v, (BUF)[lane16 * 16 + ((quad     ) ^ lane16)]); \
    s8v a1_ = __builtin_bit_cast(s8v, (BUF)[lane16 * 16 + ((quad +  4) ^ lane16)]); \
    s8v a2_ = __builtin_bit_cast(s8v, (BUF)[lane16 * 16 + ((quad +  8) ^ lane16)]); \
    s8v a3_ = __builtin_bit_cast(s8v, (BUF)[lane16 * 16 + ((quad + 12) ^ lane16)]);

#define NBACC(WT4, NCOL, ACC) \
    f4v ACC = (f4v){0.f, 0.f, 0.f, 0.f}; \
    ACC = __builtin_amdgcn_mfma_f32_16x16x32_bf16(a0_, __builtin_bit_cast(s8v, (WT4)[(NCOL) * 16 + quad     ]), ACC, 0, 0, 0); \
    ACC = __builtin_amdgcn_mfma_f32_16x16x32_bf16(a1_, __builtin_bit_cast(s8v, (WT4)[(NCOL) * 16 + quad +  4]), ACC, 0, 0, 0); \
    ACC = __builtin_amdgcn_mfma_f32_16x16x32_bf16(a2_, __builtin_bit_cast(s8v, (WT4)[(NCOL) * 16 + quad +  8]), ACC, 0, 0, 0); \
    ACC = __builtin_amdgcn_mfma_f32_16x16x32_bf16(a3_, __builtin_bit_cast(s8v, (WT4)[(NCOL) * 16 + quad + 12]), ACC, 0, 0, 0);

#define BST(EXPR, RR, COL, USPTR) { int rw_ = quad * 4 + (RR); int cc_ = (COL) >> 3; \
    (USPTR)[rw_ * 128 + (((cc_ ^ rw_)) << 3) + ((COL) & 7)] = f2bf(EXPR); }

#define LDS4R(ACC, B, COL, US) \
    BST(fmaxf(ACC[0] + (B), 0.f), 0, COL, US) BST(fmaxf(ACC[1] + (B), 0.f), 1, COL, US) \
    BST(fmaxf(ACC[2] + (B), 0.f), 2, COL, US) BST(fmaxf(ACC[3] + (B), 0.f), 3, COL, US)

#define LDS4(ACC, B, COL, US) \
    BST(ACC[0] + (B), 0, COL, US) BST(ACC[1] + (B), 1, COL, US) \
    BST(ACC[2] + (B), 2, COL, US) BST(ACC[3] + (B), 3, COL, US)

#define GBF4S(ACC, COL, PTR) \
    ((unsigned short*)(PTR))[(size_t)pr0 * HD + (COL)] = f2bf(ACC[0]); \
    ((unsigned short*)(PTR))[(size_t)pr1 * HD + (COL)] = f2bf(ACC[1]); \
    ((unsigned short*)(PTR))[(size_t)pr2 * HD + (COL)] = f2bf(ACC[2]); \
    ((unsigned short*)(PTR))[(size_t)pr3 * HD + (COL)] = f2bf(ACC[3]);

#define GF4(ACC, B, COL, PTR) \
    (PTR)[(size_t)(r0 + quad * 4 + 0) * HD + (COL)] = ACC[0] + (B); \
    (PTR)[(size_t)(r0 + quad * 4 + 1) * HD + (COL)] = ACC[1] + (B); \
    (PTR)[(size_t)(r0 + quad * 4 + 2) * HD + (COL)] = ACC[2] + (B); \
    (PTR)[(size_t)(r0 + quad * 4 + 3) * HD + (COL)] = ACC[3] + (B);

__global__ __launch_bounds__(256) void k_mlp7_mfma(
        const float* __restrict__ s1in, const __hip_bfloat16* __restrict__ wt7,
        const float* __restrict__ bb2, const float* __restrict__ bcz1,
        const float* __restrict__ bbm2, const float* __restrict__ bcz2,
        const int* __restrict__ prank,
        float* __restrict__ outA, float* __restrict__ outB,
        __hip_bfloat16* __restrict__ htb, __hip_bfloat16* __restrict__ hsb) {
    __shared__ float4 bufA4[256];  // 16 rows x 16 chunks (bf16x8) = 4 KB
    __shared__ float4 bufB4[256];
    int tid = threadIdx.x;
    int wv = tid >> 6;
    int l = tid & 63;
    int lane16 = l & 15;
    int quad = l >> 4;
    int r0 = blockIdx.x * 16;
    const float4* wt4 = (const float4*)wt7;

    int pr0 = prank[r0 + quad * 4 + 0];
    int pr1 = prank[r0 + quad * 4 + 1];
    int pr2 = prank[r0 + quad * 4 + 2];
    int pr3 = prank[r0 + quad * 4 + 3];

    {
        const float4* g4 = (const float4*)(s1in + (size_t)r0 * HD);
        float4 u0 = g4[2 * tid], u1 = g4[2 * tid + 1];
        int row_ = tid >> 4, c_ = tid & 15;
        bufA4[row_ * 16 + (c_ ^ row_)] = pack8(u0, u1);
    }
    __syncthreads();
    int col0 = wv * 32 + lane16, col1 = col0 + 16;
    unsigned short* usA = (unsigned short*)bufA4;
    unsigned short* usB = (unsigned short*)bufB4;

    {   // G1: h2 = relu(aggH @ W2 + b2) -> bufB
        AFRAGS(bufA4)
        NBACC(wt4, col0, cA) NBACC(wt4, col1, cB)
        float q0 = bb2[col0], q1 = bb2[col1];
        LDS4R(cA, q0, col0, usB) LDS4R(cB, q1, col1, usB)
    }
    __syncthreads();
    {   // G2: t = relu(h2 @ Wm1 + cz1) -> bufA
        AFRAGS(bufB4)
        const float4* wt = wt4 + 2048;
        NBACC(wt, col0, cA) NBACC(wt, col1, cB)
        float q0 = bcz1[col0], q1 = bcz1[col1];
        LDS4R(cA, q0, col0, usA) LDS4R(cB, q1, col1, usA)
    }
    __syncthreads();
    {   // G3: h = t @ Wm2 + bm2 -> bufB
        AFRAGS(bufA4)
        const float4* wt = wt4 + 2 * 2048;
        NBACC(wt, col0, cA) NBACC(wt, col1, cB)
        float q0 = bbm2[col0], q1 = bbm2[col1];
        LDS4(cA, q0, col0, usB) LDS4(cB, q1, col1, usB)
    }
    __syncthreads();
    {   // G4: ht = h @ Wtm -> sorted rows, bf16
        AFRAGS(bufB4)
        const float4* wt = wt4 + 3 * 2048;
        NBACC(wt, col0, cA) NBACC(wt, col1, cB)
        GBF4S(cA, col0, htb) GBF4S(cB, col1, htb)
    }
    {   // G5: hs = h @ Wsm -> sorted rows, bf16
        AFRAGS(bufB4)
        const float4* wt = wt4 + 4 * 2048;
        NBACC(wt, col0, cA) NBACC(wt, col1, cB)
        GBF4S(cA, col0, hsb) GBF4S(cB, col1, hsb)
    }
    {   // G6: A = h @ Wi1[:128] -> global f32 (original order)
        AFRAGS(bufB4)
        const float4* wt = wt4 + 5 * 2048;
        NBACC(wt, col0, cA) NBACC(wt, col1, cB)
        GF4(cA, 0.f, col0, outA) GF4(cB, 0.f, col1, outA)
    }
    {   // G7: B = h @ Wi1[128:256] + cz2 -> global f32 (in-place over s1)
        AFRAGS(bufB4)
        const float4* wt = wt4 + 6 * 2048;
        NBACC(wt, col0, cA) NBACC(wt, col1, cB)
        float q0 = bcz2[col0], q1 = bcz2[col1];
        GF4(cA, q0, col0, outB) GF4(cB, q1, col1, outB)
    }
}

// ===== Fused bf16-MFMA scores + masked top-2, v15 =====
// 512 threads, 8 waves = 4 row-halves (32 rows) x 2 COLUMN-halves (32 cols).
// Same 128-row blocks / tile count / total LDS traffic as v10, but each
// wave's per-tile serial chain halves (8 ds_read_b128, 16 MFMA, half merge)
// and wave-level parallelism doubles -> attacks the measured latency bound.
// Column-half pair merges top-2 states once per block via LDS at the end.
#define STG(buf, q, val) { int r_ = (q) >> 4, c_ = (q) & 15; \
    (buf)[r_ * 16 + (c_ ^ (r_ & 7))] = (val); }

#define MFMA_ __builtin_amdgcn_mfma_f32_16x16x32_bf16

#define KC2(kc, AX, AY) { \
    int co_ = (kc) * 4 + quad; \
    int bo_ = bbase + (co_ ^ brm) + nbb * 256; \
    s8v b0_ = __builtin_bit_cast(s8v, B[bo_      ]); \
    s8v b1_ = __builtin_bit_cast(s8v, B[bo_ + 256]); \
    x0 = MFMA_(AX, b0_, x0, 0, 0, 0); y0 = MFMA_(AY, b0_, y0, 0, 0, 0); \
    x1 = MFMA_(AX, b1_, x1, 0, 0, 0); y1 = MFMA_(AY, b1_, y1, 0, 0, 0); }

// general merge (boundary tiles): per-element depth mask
#define RMG(K1, K2, EL, DV) { \
    unsigned pb_ = (__builtin_bit_cast(unsigned, EL) & 0xFFFFC000u) | e_; \
    float sf_ = __builtin_bit_cast(float, (du_ < (DV)) ? pb_ : negp_); \
    K2 = __builtin_amdgcn_fmed3f(K1, K2, sf_); \
    K1 = fmaxf(K1, sf_); }

#define MGEN(nb, XA, YA) { \
    int p_ = u0 + (nbb + (nb)) * 16 + lane16; \
    int du_ = sdep[p_]; \
    unsigned e_ = 0x3FFFu - (unsigned)sidx[p_]; \
    unsigned negp_ = negbase | e_; \
    RMG(k1x0, k2x0, XA[0], dvx0) RMG(k1x1, k2x1, XA[1], dvx1) \
    RMG(k1x2, k2x2, XA[2], dvx2) RMG(k1x3, k2x3, XA[3], dvx3) \
    RMG(k1y0, k2y0, YA[0], dvy0) RMG(k1y1, k2y1, YA[1], dvy1) \
    RMG(k1y2, k2y2, YA[2], dvy2) RMG(k1y3, k2y3, YA[3], dvy3) }

// fast merge (tile fully valid for all 32 rows of the wave): no mask
#define RMF(K1, K2, EL) { \
    float sf_ = __builtin_bit_cast(float, \
        (__builtin_bit_cast(unsigned, EL) & 0xFFFFC000u) | e_); \
    K2 = __builtin_amdgcn_fmed3f(K1, K2, sf_); \
    K1 = fmaxf(K1, sf_); }

#define MFAST(nb, XA, YA) { \
    int p_ = u0 + (nbb + (nb)) * 16 + lane16; \
    unsigned e_ = 0x3FFFu - (unsigned)sidx[p_]; \
    RMF(k1x0, k2x0, XA[0]) RMF(k1x1, k2x1, XA[1]) \
    RMF(k1x2, k2x2, XA[2]) RMF(k1x3, k2x3, XA[3]) \
    RMF(k1y0, k2y0, YA[0]) RMF(k1y1, k2y1, YA[1]) \
    RMF(k1y2, k2y2, YA[2]) RMF(k1y3, k2y3, YA[3]) }

#define BF1(K1, K2, m) { \
    float o1_ = __shfl_xor(K1, m, 64); \
    float o2_ = __shfl_xor(K2, m, 64); \
    float m2_ = fmaxf(K2, o2_); \
    K2 = __builtin_amdgcn_fmed3f(K1, o1_, m2_); \
    K1 = fmaxf(K1, o1_); }

#define BFALL(m) \
    BF1(k1x0, k2x0, m) BF1(k1x1, k2x1, m) BF1(k1x2, k2x2, m) BF1(k1x3, k2x3, m) \
    BF1(k1y0, k2y0, m) BF1(k1y1, k2y1, m) BF1(k1y2, k2y2, m) BF1(k1y3, k2y3, m)

// cross-colhalf merge: top-2 of union of (K1,K2) and (O1,O2)
#define MRG(K1, K2, O1, O2) { \
    float m2_ = fmaxf(K2, (O2)); \
    K2 = __builtin_amdgcn_fmed3f(K1, (O1), m2_); \
    K1 = fmaxf(K1, (O1)); }

#define EMIT2(K1, K2, GROW) { \
    size_t o = ((size_t)seg * NN + (GROW)) * 2; \
    pv[o] = K1; pv[o + 1] = K2; }

__global__ __launch_bounds__(512) void k_score_top2_mfma(
        const __hip_bfloat16* __restrict__ htb,
        const __hip_bfloat16* __restrict__ hsb,
        const int* __restrict__ sdep, const int* __restrict__ sidx,
        const int* __restrict__ bofs,
        float* __restrict__ pv) {
    __shared__ float4 Bs4[2][64 * 16];   // 32 KB double buffer (B only)
    int tid = threadIdx.x;
    int w = tid >> 6;        // 0..7
    int l = tid & 63;
    int lane16 = l & 15;
    int quad = l >> 4;
    int rh = w >> 1;         // row-half 0..3 (32 rows each)
    int ch = w & 1;          // column-half 0..1 (32 cols each)
    int nbb = ch * 2;        // nb base: this wave's cand cols nbb*16..+31
    int rb = (int)gridDim.x - 1 - (int)blockIdx.x;  // heavy blocks first
    int row0 = rb * 128;
    int seg = blockIdx.y;
    const unsigned negbase = __builtin_bit_cast(unsigned, NEGV) & 0xFFFFC000u;

    // balanced split: ns = ceil(nt/12) active segments (<= 16), ~12 tiles ea.
    int dmax = sdep[row0 + 127];
    int lim = bofs[dmax];
    int nt = (lim + 63) >> 6;               // total tiles, <= 192
    int ns = (nt + 11) / 12;
    if (ns < 1) ns = 1;
    if (seg >= ns) {
        if (tid < 128) {
            int grow = sidx[row0 + tid];
            size_t o = ((size_t)seg * NN + grow) * 2;
            pv[o]     = __builtin_bit_cast(float, negbase | 0x3FFFu);
            pv[o + 1] = __builtin_bit_cast(float, negbase | 0x3FFEu);
        }
        return;
    }
    int t0 = (seg * nt) / ns;
    int t1 = ((seg + 1) * nt) / ns;

    // A fragments: 32 sorted target rows per wave, two 16-row MFMA groups.
    int rbase = row0 + rh * 32;
    s8v ax0, ax1, ax2, ax3, ay0, ay1, ay2, ay3;
    {
        const float4* gx = (const float4*)(htb + (size_t)(rbase + lane16) * HD);
        ax0 = __builtin_bit_cast(s8v, gx[quad]);
        ax1 = __builtin_bit_cast(s8v, gx[4 + quad]);
        ax2 = __builtin_bit_cast(s8v, gx[8 + quad]);
        ax3 = __builtin_bit_cast(s8v, gx[12 + quad]);
        const float4* gy = (const float4*)(htb + (size_t)(rbase + 16 + lane16) * HD);
        ay0 = __builtin_bit_cast(s8v, gy[quad]);
        ay1 = __builtin_bit_cast(s8v, gy[4 + quad]);
        ay2 = __builtin_bit_cast(s8v, gy[8 + quad]);
        ay3 = __builtin_bit_cast(s8v, gy[12 + quad]);
    }
    if (t0 < t1) {   // stage first tile (512 threads x 2 float4)
        float4* B0 = Bs4[t0 & 1];
        const float4* gb = (const float4*)(hsb + (size_t)(t0 * 64) * HD);
        float4 b0_ = gb[tid], b1_ = gb[tid + 512];
        STG(B0, tid, b0_) STG(B0, tid + 512, b1_)
    }

    int bbase = lane16 * 16, brm = lane16 & 7;

    int dvx0 = sdep[rbase + quad * 4 + 0];
    int dvx1 = sdep[rbase + quad * 4 + 1];
    int dvx2 = sdep[rbase + quad * 4 + 2];
    int dvx3 = sdep[rbase + quad * 4 + 3];
    int dvy0 = sdep[rbase + 16 + quad * 4 + 0];
    int dvy1 = sdep[rbase + 16 + quad * 4 + 1];
    int dvy2 = sdep[rbase + 16 + quad * 4 + 2];
    int dvy3 = sdep[rbase + 16 + quad * 4 + 3];
    // wave window: cands < lim_lo valid for EVERY row; >= lim_hi for none.
    int lim_lo = bofs[sdep[rbase]];
    int lim_hi = bofs[sdep[rbase + 31]];

    // defaults: packed NEGV for orig u=0 (k1) and u=1 (k2) live ONLY in the
    // ch==0 wave (lane16==0); ch==1 inits to -inf so the cross-half MRG
    // reproduces v10's emitted values exactly on empty rows.
    float ki1 = (ch == 0 && lane16 == 0)
        ? __builtin_bit_cast(float, negbase | 0x3FFFu) : -3.4e38f;
    float ki2 = (ch == 0 && lane16 == 0)
        ? __builtin_bit_cast(float, negbase | 0x3FFEu) : -3.4e38f;
    float k1x0 = ki1, k1x1 = ki1, k1x2 = ki1, k1x3 = ki1;
    float k1y0 = ki1, k1y1 = ki1, k1y2 = ki1, k1y3 = ki1;
    float k2x0 = ki2, k2x1 = ki2, k2x2 = ki2, k2x3 = ki2;
    float k2y0 = ki2, k2y1 = ki2, k2y2 = ki2, k2y3 = ki2;

    float4 p0, p1;
    for (int t = t0; t < t1; ++t) {
        int u0 = t * 64;
        __syncthreads();
        if (t + 1 < t1) {
            const float4* g = (const float4*)(hsb + (size_t)(u0 + 64) * HD);
            p0 = g[tid]; p1 = g[tid + 512];
        }
        if (u0 < lim_hi) {          // wave-uniform: tile matters for >=1 row
            const float4* B = Bs4[t & 1];
            f4v x0 = (f4v){0.f, 0.f, 0.f, 0.f};
            f4v x1 = (f4v){0.f, 0.f, 0.f, 0.f};
            f4v y0 = (f4v){0.f, 0.f, 0.f, 0.f};
            f4v y1 = (f4v){0.f, 0.f, 0.f, 0.f};
            KC2(0, ax0, ay0) KC2(1, ax1, ay1) KC2(2, ax2, ay2) KC2(3, ax3, ay3)
            if (u0 + 64 <= lim_lo) {   // fully valid for all 32 rows
                MFAST(0, x0, y0) MFAST(1, x1, y1)
            } else {                   // boundary: per-element depth mask
                MGEN(0, x0, y0) MGEN(1, x1, y1)
            }
        }
        if (t + 1 < t1) {
            float4* Bn = Bs4[(t + 1) & 1];
            STG(Bn, tid, p0) STG(Bn, tid + 512, p1)
        }
    }

    // cross-colhalf merge: ch==1 publishes its 16 k-regs; ch==0 merges.
    __syncthreads();
    float* S = (float*)Bs4;             // 4 rowhalves x 16 regs x 64 lanes
    if (ch == 1) {
        int base = rh * 1024 + l;
        S[base +  0 * 64] = k1x0; S[base +  1 * 64] = k1x1;
        S[base +  2 * 64] = k1x2; S[base +  3 * 64] = k1x3;
        S[base +  4 * 64] = k1y0; S[base +  5 * 64] = k1y1;
        S[base +  6 * 64] = k1y2; S[base +  7 * 64] = k1y3;
        S[base +  8 * 64] = k2x0; S[base +  9 * 64] = k2x1;
        S[base + 10 * 64] = k2x2; S[base + 11 * 64] = k2x3;
        S[base + 12 * 64] = k2y0; S[base + 13 * 64] = k2y1;
        S[base + 14 * 64] = k2y2; S[base + 15 * 64] = k2y3;
    }
    __syncthreads();
    if (ch == 0) {
        int base = rh * 1024 + l;
        MRG(k1x0, k2x0, S[base +  0 * 64], S[base +  8 * 64])
        MRG(k1x1, k2x1, S[base +  1 * 64], S[base +  9 * 64])
        MRG(k1x2, k2x2, S[base +  2 * 64], S[base + 10 * 64])
        MRG(k1x3, k2x3, S[base +  3 * 64], S[base + 11 * 64])
        MRG(k1y0, k2y0, S[base +  4 * 64], S[base + 12 * 64])
        MRG(k1y1, k2y1, S[base +  5 * 64], S[base + 13 * 64])
        MRG(k1y2, k2y2, S[base +  6 * 64], S[base + 14 * 64])
        MRG(k1y3, k2y3, S[base +  7 * 64], S[base + 15 * 64])

        BFALL(1) BFALL(2) BFALL(4) BFALL(8)

        if (lane16 == 0) {
            int gbse = rbase + quad * 4;
            EMIT2(k1x0, k2x0, sidx[gbse + 0])
            EMIT2(k1x1, k2x1, sidx[gbse + 1])
            EMIT2(k1x2, k2x2, sidx[gbse + 2])
            EMIT2(k1x3, k2x3, sidx[gbse + 3])
            EMIT2(k1y0, k2y0, sidx[gbse + 16])
            EMIT2(k1y1, k2y1, sidx[gbse + 17])
            EMIT2(k1y2, k2y2, sidx[gbse + 18])
            EMIT2(k1y3, k2y3, sidx[gbse + 19])
        }
    }
}

// ONE kernel writes ALL outputs (f32): parallel packed merge (r15-proven).
__global__ __launch_bounds__(256) void k_final(const float* __restrict__ pv,
                                               const int* __restrict__ ntype,
                                               const int* __restrict__ ndepth,
                                               const float* __restrict__ A,
                                               const float* __restrict__ B,
                                               const float* __restrict__ Wi2,
                                               const float* __restrict__ bi2,
                                               float* __restrict__ out) {
    int tid = threadIdx.x;
    int lane = tid & 63;
    int v = blockIdx.x * 4 + (tid >> 6);

    float k1 = -3.4e38f;
    if (lane < 32) {
        k1 = pv[((size_t)(lane >> 1) * NN + v) * 2 + (lane & 1)];
    }
    float k2 = -3.4e38f;
#pragma unroll
    for (int m = 1; m <= 16; m <<= 1) {
        float o1 = __shfl_xor(k1, m, 64);
        float o2 = __shfl_xor(k2, m, 64);
        float m2 = fmaxf(k2, o2);
        k2 = __builtin_amdgcn_fmed3f(k1, o1, m2);
        k1 = fmaxf(k1, o1);
    }
    float K1 = __shfl(k1, 0, 64);
    float K2 = __shfl(k2, 0, 64);
    unsigned b1 = __builtin_bit_cast(unsigned, K1);
    unsigned b2 = __builtin_bit_cast(unsigned, K2);
    int I1 = 0x3FFF - (int)(b1 & 0x3FFFu);
    int I2 = 0x3FFF - (int)(b2 & 0x3FFFu);

    if (lane == 0) {
        int tp = ntype[v];
        bool tv = (tp != 0) && (ndepth[v] > 0) && (K1 > -5.0e8f);  // NEG/2
        out[2 * NN + 2 * v]     = K1;
        out[2 * NN + 2 * v + 1] = K2;
        out[4 * NN + 2 * v]     = (float)I1;
        out[4 * NN + 2 * v + 1] = (float)I2;
        out[6 * NN + 2 * v]     = tv ? 1.f : 0.f;
        out[6 * NN + 2 * v + 1] = (tv && tp == 2) ? 1.f : 0.f;
    }

    int u1 = min(max(I1, 0), NN - 1);
    int u2 = min(max(I2, 0), NN - 1);
    const float2* A2p = (const float2*)A;
    float2 av1 = A2p[(size_t)u1 * 64 + lane];
    float2 av2 = A2p[(size_t)u2 * 64 + lane];
    float2 bv = ((const float2*)B)[(size_t)v * 64 + lane];
    float2 wv = ((const float2*)Wi2)[lane];
    float bias = bi2[0];
    float a1 = fmaf(fmaxf(av1.x + bv.x, 0.f), wv.x,
                    fmaxf(av1.y + bv.y, 0.f) * wv.y);
    float a2 = fmaf(fmaxf(av2.x + bv.x, 0.f), wv.x,
                    fmaxf(av2.y + bv.y, 0.f) * wv.y);
#pragma unroll
    for (int off = 32; off > 0; off >>= 1) {
        a1 += __shfl_down(a1, off);
        a2 += __shfl_down(a2, off);
    }
    if (lane == 0) {
        out[2 * v]     = 1.f / (1.f + expf(-(a1 + bias)));
        out[2 * v + 1] = 1.f / (1.f + expf(-(a2 + bias)));
    }
}

extern "C" void kernel_launch(void* const* d_in, const int* in_sizes, int n_in,
                              void* d_out, int out_size, void* d_ws, size_t ws_size,
                              hipStream_t stream) {
    (void)in_sizes; (void)n_in; (void)out_size; (void)ws_size;
    const float* x   = (const float*)d_in[0];
    const float* z   = (const float*)d_in[1];
    const int* ntype = (const int*)d_in[2];
    const int* ndep  = (const int*)d_in[3];
    const int* eidx  = (const int*)d_in[4];
    const float* W1  = (const float*)d_in[5];
    const float* b1  = (const float*)d_in[6];
    const float* W2  = (const float*)d_in[7];
    const float* b2  = (const float*)d_in[8];
    const float* Wm1 = (const float*)d_in[9];
    const float* bm1 = (const float*)d_in[10];
    const float* Wm2 = (const float*)d_in[11];
    const float* bm2 = (const float*)d_in[12];
    const float* Wsm = (const float*)d_in[13];
    const float* Wtm = (const float*)d_in[14];
    const float* Wi1 = (const float*)d_in[15];
    const float* bi1 = (const float*)d_in[16];
    const float* Wi2 = (const float*)d_in[17];
    const float* bi2 = (const float*)d_in[18];
    float* out = (float*)d_out;

    const int* esrc = eidx;
    const int* edst = eidx + NE;

    // Workspace layout (~24.5 MiB). The pi spacer (unused S2N ints) hosts
    // the line-padded cnt/dcur counters (stride 16 -> 1 counter per 64B line).
    const size_t S2N = (size_t)SEG * 2 * NN;  // 393216
    float* ws = (float*)d_ws;
    float* pv     = ws;                       // [S2N] f (packed scores)
    int*   pi     = (int*)(pv + S2N);         // [S2N] i (spacer)
    int*   cnt    = pi;                       // [64*16] padded depth counts
    int*   dcur   = pi + 1024;                // [64*16] padded depth cursors
    int*   degi   = pi + S2N;                 // [NN]   (memset)
    float* inv    = (float*)(degi + NN + 64); // [NN]  (old cnt slot = pad)
    float* agg2   = inv + NN;                 // [2NN]
    float* cz1    = agg2 + 2 * NN;            // [128]
    float* cz2    = cz1 + 128;                // [128]
    int*   offs   = (int*)(cz2 + 128);        // [NN+16]
    int*   cursor = offs + NN + 16;           // [NN]
    int*   bofs   = cursor + NN;              // [80]
    int*   sidx   = bofs + 80 + 64;           // [NN] (old dcur slot = pad)
    int*   sdep   = sidx + NN;                // [NN]
    int*   prank  = sdep + NN;                // [NN]
    int*   ebsrc  = prank + NN;               // [NE]
    float* ebw    = (float*)(ebsrc + NE);     // [NE]
    __hip_bfloat16* wt7 = (__hip_bfloat16*)(ebw + NE);  // [7*16384] bf16
    size_t F = (size_t)NN * HD;
    float* s0 = (float*)(wt7 + 7 * 16384);    // h1b (bf16) -> {htb_s, hsb_s}
    float* s1 = s0 + F;                       // aggH -> B (in-place)
    float* s2 = s1 + F;                       // A
    unsigned short* h1b = (unsigned short*)s0;
    __hip_bfloat16* htb = (__hip_bfloat16*)s0;
    __hip_bfloat16* hsb = htb + F;

    hipMemsetAsync(degi, 0, NN * sizeof(int), stream);
    hipMemsetAsync(cnt, 0, 1024 * sizeof(int), stream);
    k_counts_wz<<<NE / 256 + NN / 256 + 448 + 1, 256, 0, stream>>>(
        edst, ndep, W2, Wm1, Wm2, Wtm, Wsm, Wi1, z, bm1, bi1,
        degi, cnt, wt7, cz1, cz2);
    k_prefix<<<1, 1024, 0, stream>>>(degi, cnt, x, inv, agg2, offs, cursor, bofs, dcur);
    k_bucket_scatter<<<NE / 256 + NN / 256, 256, 0, stream>>>(
        esrc, edst, ndep, inv, cursor, ebsrc, ebw, dcur, sidx, sdep, prank);
    k_gather2<<<NN * 8 / 256, 256, 0, stream>>>(offs, ebsrc, ebw, x, agg2);
    k_lin1<<<NN * HD / 256, 256, 0, stream>>>(agg2, W1, b1, inv, h1b, s1);
    k_gatherH<<<NN / 4, 256, 0, stream>>>(offs, ebsrc, ebw, h1b, s1);
    k_mlp7_mfma<<<NN / 16, 256, 0, stream>>>(s1, wt7, b2, cz1, bm2, cz2,
                                             prank, s2, s1, htb, hsb);
    k_score_top2_mfma<<<dim3(NN / 128, SEG), 512, 0, stream>>>(
        htb, hsb, sdep, sidx, bofs, pv);
    k_final<<<NN / 4, 256, 0, stream>>>(pv, ntype, ndep, s2, s1, Wi2, bi2, out);
}

// Round 8
// 225.559 us; speedup vs baseline: 1.0406x; 1.0406x over previous
//
#include <hip/hip_runtime.h>
#include <hip/hip_bf16.h>

#define NN 12288
#define NE 196608
#define HD 128
#define ZD 128
#define NEGV (-1.0e9f)
#define SEG 16

using s8v = __attribute__((ext_vector_type(8))) short;  // 8 bf16 = 4 VGPRs
using f4v = __attribute__((ext_vector_type(4))) float;  // 4 fp32 acc
using i4v = __attribute__((ext_vector_type(4))) int;

__device__ __forceinline__ unsigned short f2bf(float f) {
    return __builtin_bit_cast(unsigned short, __float2bfloat16(f));
}
__device__ __forceinline__ float4 pack8(float4 a, float4 b) {
    unsigned p0 = ((unsigned)f2bf(a.y) << 16) | f2bf(a.x);
    unsigned p1 = ((unsigned)f2bf(a.w) << 16) | f2bf(a.z);
    unsigned p2 = ((unsigned)f2bf(b.y) << 16) | f2bf(b.x);
    unsigned p3 = ((unsigned)f2bf(b.w) << 16) | f2bf(b.z);
    i4v r = (i4v){(int)p0, (int)p1, (int)p2, (int)p3};
    return __builtin_bit_cast(float4, r);
}

// Mega split-grid of INDEPENDENT prep work:
// [0,768): edge in-degree count; [768,816): depth-bucket count (LDS hist ->
// line-padded counters); [816,1264): 7x weight transpose; [1264]: cz1/cz2.
__global__ __launch_bounds__(256) void k_counts_wz(
        const int* __restrict__ edst, const int* __restrict__ ndep,
        const float* __restrict__ W2, const float* __restrict__ Wm1,
        const float* __restrict__ Wm2, const float* __restrict__ Wtm,
        const float* __restrict__ Wsm, const float* __restrict__ Wi1,
        const float* __restrict__ z, const float* __restrict__ bm1,
        const float* __restrict__ bi1,
        int* degi, int* cnt, __hip_bfloat16* __restrict__ wt7,
        float* cz1, float* cz2) {
    __shared__ int lh[64];
    int tid = threadIdx.x;
    int bid = blockIdx.x;
    if (bid < NE / 256) {
        int e = bid * 256 + tid;
        atomicAdd(&degi[edst[e]], 1);
    } else if (bid < NE / 256 + NN / 256) {
        // depth histogram: LDS-aggregate, then 1 global atomic per depth per
        // block onto stride-16 (one-per-cacheline) counters -> no cross-XCD
        // same-line atomic ping-pong.
        if (tid < 64) lh[tid] = 0;
        __syncthreads();
        int v = (bid - NE / 256) * 256 + tid;
        atomicAdd(&lh[ndep[v]], 1);
        __syncthreads();
        if (tid < 64) {
            int c = lh[tid];
            if (c) atomicAdd(&cnt[tid * 16], c);
        }
    } else if (bid < NE / 256 + NN / 256 + 448) {
        int flat = (bid - NE / 256 - NN / 256) * 256 + tid;  // < 7*16384
        int g = flat >> 14;
        int rem = flat & 16383;
        int k = rem >> 7, n = rem & 127;
        const float* src;
        if (g == 0) src = W2;
        else if (g == 1) src = Wm1;
        else if (g == 2) src = Wm2;
        else if (g == 3) src = Wtm;
        else if (g == 4) src = Wsm;
        else if (g == 5) src = Wi1;
        else src = Wi1 + 128 * HD;
        wt7[(g << 14) + n * 128 + k] = __float2bfloat16(src[rem]);
    } else {
        int j = tid & 127;
        const float* W = (tid < 128) ? (Wm1 + HD * HD) : (Wi1 + 2 * HD * HD);
        float A0 = 0.f, A1 = 0.f, A2 = 0.f, A3 = 0.f;
        for (int k = 0; k < ZD; k += 4) {
            A0 = fmaf(z[k],     W[(k    ) * HD + j], A0);
            A1 = fmaf(z[k + 1], W[(k + 1) * HD + j], A1);
            A2 = fmaf(z[k + 2], W[(k + 2) * HD + j], A2);
            A3 = fmaf(z[k + 3], W[(k + 3) * HD + j], A3);
        }
        float r = (A0 + A1) + (A2 + A3);
        if (tid < 128) cz1[j] = r + bm1[j];
        else           cz2[j] = r + bi1[j];
    }
}

// ONE block, 1024 threads: CSR offsets (+cursor), inv = rsqrt(deg+1), agg2
// self term, plus (tid 0) the 64-bucket depth scan -> bofs/dcur.
// v2: LDS-staged, fully coalesced global access.
__global__ __launch_bounds__(1024) void k_prefix(const int* __restrict__ degi,
                                                 const int* __restrict__ cnt,
                                                 const float* __restrict__ x,
                                                 float* inv, float* agg2,
                                                 int* offs, int* cursor,
                                                 int* bofs, int* dcur) {
    __shared__ int ldeg[NN];     // 48 KB: degi, then overwritten by prefix
    __shared__ int part[1024];   // 4 KB
    __shared__ int stot;
    int tid = threadIdx.x;
#pragma unroll
    for (int k = 0; k < 12; ++k)          // coalesced: lane-stride 4B
        ldeg[k * 1024 + tid] = degi[k * 1024 + tid];
    __syncthreads();
    int base = tid * 12;
    int s = 0;
#pragma unroll
    for (int k = 0; k < 12; ++k) s += ldeg[base + k];
    part[tid] = s;
    __syncthreads();
    for (int off = 1; off < 1024; off <<= 1) {
        int v = (tid >= off) ? part[tid - off] : 0;
        __syncthreads();
        part[tid] += v;
        __syncthreads();
    }
    int run = part[tid] - s;  // exclusive base for this thread's 12 elems
#pragma unroll
    for (int k = 0; k < 12; ++k) {        // overwrite LDS with excl prefix
        int d = ldeg[base + k];
        ldeg[base + k] = run;
        run += d;
    }
    if (tid == 1023) stot = run;          // grand total
    __syncthreads();
    int total = stot;
    const float2* X2 = (const float2*)x;
    float2* A2 = (float2*)agg2;
#pragma unroll
    for (int k = 0; k < 12; ++k) {        // coalesced output phase
        int i = k * 1024 + tid;
        int p = ldeg[i];
        int nxt = (i < NN - 1) ? ldeg[i + 1] : total;
        int d = nxt - p;                  // recover degree
        offs[i] = p;
        cursor[i] = p;
        float iv = rsqrtf((float)(d + 1));
        inv[i] = iv;
        float w = iv * iv;
        float2 xv = X2[i];
        float2 av; av.x = xv.x * w; av.y = xv.y * w;
        A2[i] = av;
    }
    if (tid == 0) {
        offs[NN] = total;
        int r = 0;                        // depth-bucket exclusive scan
        for (int d = 0; d < 64; ++d) {
            bofs[d] = r;
            dcur[d * 16] = r;
            r += cnt[d * 16];
        }
        bofs[64] = r;
    }
}

// Split grid: blocks [0,768) bucket edges; [768,816) depth-sort scatter
// (LDS local-rank + one padded global atomic per depth per block).
__global__ __launch_bounds__(256) void k_bucket_scatter(
        const int* __restrict__ esrc, const int* __restrict__ edst,
        const int* __restrict__ ndep, const float* __restrict__ inv,
        int* cursor, int* ebsrc, float* ebw,
        int* dcur, int* sidx, int* sdep, int* prank) {
    __shared__ int lh[64];
    __shared__ int lbase[64];
    int tid = threadIdx.x;
    if (blockIdx.x < NE / 256) {
        int e = blockIdx.x * 256 + tid;
        int u = esrc[e], v = edst[e];
        int pos = atomicAdd(&cursor[v], 1);
        ebsrc[pos] = u;
        ebw[pos] = inv[u] * inv[v];
    } else {
        if (tid < 64) lh[tid] = 0;
        __syncthreads();
        int v = (blockIdx.x - NE / 256) * 256 + tid;
        int d = ndep[v];
        int r = atomicAdd(&lh[d], 1);          // local rank within block
        __syncthreads();
        if (tid < 64) {
            int c = lh[tid];
            if (c) lbase[tid] = atomicAdd(&dcur[tid * 16], c);
        }
        __syncthreads();
        int p = lbase[d] + r;
        sidx[p] = v;
        sdep[p] = d;
        prank[v] = p;
    }
}

// FUSED layer-1 gather + lin1: one block owns 32 nodes. Phase 1: 8 lanes per
// node gather edges (seed from agg2, written by k_prefix) -> LDS. Phase 2:
// h1b = relu(agg @ W1 + b1) (bf16) and aggH self-loop seed, straight from
// LDS. Removes the lin1 launch + the agg2 global round-trip.
__global__ __launch_bounds__(256) void k_gl1(const int* __restrict__ offs,
                                             const int* __restrict__ ebsrc,
                                             const float* __restrict__ ebw,
                                             const float* __restrict__ x,
                                             const float* __restrict__ agg2,
                                             const float* __restrict__ W1,
                                             const float* __restrict__ b1,
                                             const float* __restrict__ inv,
                                             unsigned short* h1b, float* aggH) {
    __shared__ float2 la[32];
    int tid = threadIdx.x;
    int v0 = blockIdx.x * 32;
    {   // phase 1: edge gather, 8 lanes/node
        int nb = tid >> 3;
        int sl = tid & 7;
        int v = v0 + nb;
        int b = offs[v], e = offs[v + 1];
        const float2* X2 = (const float2*)x;
        float ax = 0.f, ay = 0.f;
        for (int k = b + sl; k < e; k += 8) {
            int u = ebsrc[k];
            float w = ebw[k];
            float2 xv = X2[u];
            ax = fmaf(xv.x, w, ax);
            ay = fmaf(xv.y, w, ay);
        }
#pragma unroll
        for (int m = 1; m < 8; m <<= 1) {   // 8-lane groups are lane-aligned
            ax += __shfl_xor(ax, m, 64);
            ay += __shfl_xor(ay, m, 64);
        }
        if (sl == 0) {
            float2 seed = ((const float2*)agg2)[v];  // self term (k_prefix)
            seed.x += ax; seed.y += ay;
            la[nb] = seed;
        }
    }
    __syncthreads();
    {   // phase 2: 32 nodes x 128 cols = 4096 outputs, 16 per thread
#pragma unroll
        for (int k = 0; k < 16; ++k) {
            int idx = k * 256 + tid;
            int vloc = idx >> 7, j = idx & 127;
            float2 a = la[vloc];
            float hv = fmaxf(fmaf(a.x, W1[j], fmaf(a.y, W1[HD + j], b1[j])), 0.f);
            int t = (v0 + vloc) * HD + j;
            h1b[t] = f2bf(hv);
            float iv = inv[v0 + vloc];
            aggH[t] = hv * iv * iv;
        }
    }
}

// Layer-2 aggregation: one WAVE per node, bf16 rows, 4x-unrolled.
__global__ __launch_bounds__(256) void k_gatherH(const int* __restrict__ offs,
                                                 const int* __restrict__ ebsrc,
                                                 const float* __restrict__ ebw,
                                                 const unsigned short* __restrict__ h1b,
                                                 float* aggH) {
    int tid = threadIdx.x;
    int lane = tid & 63;
    int v = blockIdx.x * 4 + (tid >> 6);
    const unsigned* H1 = (const unsigned*)h1b;
    float2* A2 = (float2*)aggH;
    float2 acc = A2[(size_t)v * 64 + lane];
    int b = offs[v], e = offs[v + 1];
    int k = b;
    for (; k + 4 <= e; k += 4) {
        int u0 = ebsrc[k], u1 = ebsrc[k + 1], u2 = ebsrc[k + 2], u3 = ebsrc[k + 3];
        float w0 = ebw[k], w1 = ebw[k + 1], w2 = ebw[k + 2], w3 = ebw[k + 3];
        unsigned hb0 = H1[(size_t)u0 * 64 + lane];
        unsigned hb1 = H1[(size_t)u1 * 64 + lane];
        unsigned hb2 = H1[(size_t)u2 * 64 + lane];
        unsigned hb3 = H1[(size_t)u3 * 64 + lane];
        acc.x = fmaf(__builtin_bit_cast(float, hb0 << 16), w0, acc.x);
        acc.y = fmaf(__builtin_bit_cast(float, hb0 & 0xFFFF0000u), w0, acc.y);
        acc.x = fmaf(__builtin_bit_cast(float, hb1 << 16), w1, acc.x);
        acc.y = fmaf(__builtin_bit_cast(float, hb1 & 0xFFFF0000u), w1, acc.y);
        acc.x = fmaf(__builtin_bit_cast(float, hb2 << 16), w2, acc.x);
        acc.y = fmaf(__builtin_bit_cast(float, hb2 & 0xFFFF0000u), w2, acc.y);
        acc.x = fmaf(__builtin_bit_cast(float, hb3 << 16), w3, acc.x);
        acc.y = fmaf(__builtin_bit_cast(float, hb3 & 0xFFFF0000u), w3, acc.y);
    }
    for (; k < e; ++k) {
        int u = ebsrc[k];
        float w = ebw[k];
        unsigned hb = H1[(size_t)u * 64 + lane];
        acc.x = fmaf(__builtin_bit_cast(float, hb << 16), w, acc.x);
        acc.y = fmaf(__builtin_bit_cast(float, hb & 0xFFFF0000u), w, acc.y);
    }
    A2[(size_t)v * 64 + lane] = acc;
}

// ===== Fused 7-GEMM MLP chain on MFMA (r10-proven; ht/hs scatter to sorted
// row positions via prank) =====
#define AFRAGS(BUF) \
    s8v a0_ = __builtin_bit_cast(s8v, (BUF)[lane16 * 16 + ((quad     ) ^ lane16)]); \
    s8v a1_ = __builtin_bit_cast(s8v, (BUF)[lane16 * 16 + ((quad +  4) ^ lane16)]); \
    s8v a2_ = __builtin_bit_cast(s8v, (BUF)[lane16 * 16 + ((quad +  8) ^ lane16)]); \
    s8v a3_ = __builtin_bit_cast(s8v, (BUF)[lane16 * 16 + ((quad + 12) ^ lane16)]);

#define NBACC(WT4, NCOL, ACC) \
    f4v ACC = (f4v){0.f, 0.f, 0.f, 0.f}; \
    ACC = __builtin_amdgcn_mfma_f32_16x16x32_bf16(a0_, __builtin_bit_cast(s8v, (WT4)[(NCOL) * 16 + quad     ]), ACC, 0, 0, 0); \
    ACC = __builtin_amdgcn_mfma_f32_16x16x32_bf16(a1_, __builtin_bit_cast(s8v, (WT4)[(NCOL) * 16 + quad +  4]), ACC, 0, 0, 0); \
    ACC = __builtin_amdgcn_mfma_f32_16x16x32_bf16(a2_, __builtin_bit_cast(s8v, (WT4)[(NCOL) * 16 + quad +  8]), ACC, 0, 0, 0); \
    ACC = __builtin_amdgcn_mfma_f32_16x16x32_bf16(a3_, __builtin_bit_cast(s8v, (WT4)[(NCOL) * 16 + quad + 12]), ACC, 0, 0, 0);

#define BST(EXPR, RR, COL, USPTR) { int rw_ = quad * 4 + (RR); int cc_ = (COL) >> 3; \
    (USPTR)[rw_ * 128 + (((cc_ ^ rw_)) << 3) + ((COL) & 7)] = f2bf(EXPR); }

#define LDS4R(ACC, B, COL, US) \
    BST(fmaxf(ACC[0] + (B), 0.f), 0, COL, US) BST(fmaxf(ACC[1] + (B), 0.f), 1, COL, US) \
    BST(fmaxf(ACC[2] + (B), 0.f), 2, COL, US) BST(fmaxf(ACC[3] + (B), 0.f), 3, COL, US)

#define LDS4(ACC, B, COL, US) \
    BST(ACC[0] + (B), 0, COL, US) BST(ACC[1] + (B), 1, COL, US) \
    BST(ACC[2] + (B), 2, COL, US) BST(ACC[3] + (B), 3, COL, US)

#define GBF4S(ACC, COL, PTR) \
    ((unsigned short*)(PTR))[(size_t)pr0 * HD + (COL)] = f2bf(ACC[0]); \
    ((unsigned short*)(PTR))[(size_t)pr1 * HD + (COL)] = f2bf(ACC[1]); \
    ((unsigned short*)(PTR))[(size_t)pr2 * HD + (COL)] = f2bf(ACC[2]); \
    ((unsigned short*)(PTR))[(size_t)pr3 * HD + (COL)] = f2bf(ACC[3]);

#define GF4(ACC, B, COL, PTR) \
    (PTR)[(size_t)(r0 + quad * 4 + 0) * HD + (COL)] = ACC[0] + (B); \
    (PTR)[(size_t)(r0 + quad * 4 + 1) * HD + (COL)] = ACC[1] + (B); \
    (PTR)[(size_t)(r0 + quad * 4 + 2) * HD + (COL)] = ACC[2] + (B); \
    (PTR)[(size_t)(r0 + quad * 4 + 3) * HD + (COL)] = ACC[3] + (B);

__global__ __launch_bounds__(256) void k_mlp7_mfma(
        const float* __restrict__ s1in, const __hip_bfloat16* __restrict__ wt7,
        const float* __restrict__ bb2, const float* __restrict__ bcz1,
        const float* __restrict__ bbm2, const float* __restrict__ bcz2,
        const int* __restrict__ prank,
        float* __restrict__ outA, float* __restrict__ outB,
        __hip_bfloat16* __restrict__ htb, __hip_bfloat16* __restrict__ hsb) {
    __shared__ float4 bufA4[256];  // 16 rows x 16 chunks (bf16x8) = 4 KB
    __shared__ float4 bufB4[256];
    int tid = threadIdx.x;
    int wv = tid >> 6;
    int l = tid & 63;
    int lane16 = l & 15;
    int quad = l >> 4;
    int r0 = blockIdx.x * 16;
    const float4* wt4 = (const float4*)wt7;

    int pr0 = prank[r0 + quad * 4 + 0];
    int pr1 = prank[r0 + quad * 4 + 1];
    int pr2 = prank[r0 + quad * 4 + 2];
    int pr3 = prank[r0 + quad * 4 + 3];

    {
        const float4* g4 = (const float4*)(s1in + (size_t)r0 * HD);
        float4 u0 = g4[2 * tid], u1 = g4[2 * tid + 1];
        int row_ = tid >> 4, c_ = tid & 15;
        bufA4[row_ * 16 + (c_ ^ row_)] = pack8(u0, u1);
    }
    __syncthreads();
    int col0 = wv * 32 + lane16, col1 = col0 + 16;
    unsigned short* usA = (unsigned short*)bufA4;
    unsigned short* usB = (unsigned short*)bufB4;

    {   // G1: h2 = relu(aggH @ W2 + b2) -> bufB
        AFRAGS(bufA4)
        NBACC(wt4, col0, cA) NBACC(wt4, col1, cB)
        float q0 = bb2[col0], q1 = bb2[col1];
        LDS4R(cA, q0, col0, usB) LDS4R(cB, q1, col1, usB)
    }
    __syncthreads();
    {   // G2: t = relu(h2 @ Wm1 + cz1) -> bufA
        AFRAGS(bufB4)
        const float4* wt = wt4 + 2048;
        NBACC(wt, col0, cA) NBACC(wt, col1, cB)
        float q0 = bcz1[col0], q1 = bcz1[col1];
        LDS4R(cA, q0, col0, usA) LDS4R(cB, q1, col1, usA)
    }
    __syncthreads();
    {   // G3: h = t @ Wm2 + bm2 -> bufB
        AFRAGS(bufA4)
        const float4* wt = wt4 + 2 * 2048;
        NBACC(wt, col0, cA) NBACC(wt, col1, cB)
        float q0 = bbm2[col0], q1 = bbm2[col1];
        LDS4(cA, q0, col0, usB) LDS4(cB, q1, col1, usB)
    }
    __syncthreads();
    {   // G4: ht = h @ Wtm -> sorted rows, bf16
        AFRAGS(bufB4)
        const float4* wt = wt4 + 3 * 2048;
        NBACC(wt, col0, cA) NBACC(wt, col1, cB)
        GBF4S(cA, col0, htb) GBF4S(cB, col1, htb)
    }
    {   // G5: hs = h @ Wsm -> sorted rows, bf16
        AFRAGS(bufB4)
        const float4* wt = wt4 + 4 * 2048;
        NBACC(wt, col0, cA) NBACC(wt, col1, cB)
        GBF4S(cA, col0, hsb) GBF4S(cB, col1, hsb)
    }
    {   // G6: A = h @ Wi1[:128] -> global f32 (original order)
        AFRAGS(bufB4)
        const float4* wt = wt4 + 5 * 2048;
        NBACC(wt, col0, cA) NBACC(wt, col1, cB)
        GF4(cA, 0.f, col0, outA) GF4(cB, 0.f, col1, outA)
    }
    {   // G7: B = h @ Wi1[128:256] + cz2 -> global f32 (in-place over s1)
        AFRAGS(bufB4)
        const float4* wt = wt4 + 6 * 2048;
        NBACC(wt, col0, cA) NBACC(wt, col1, cB)
        float q0 = bcz2[col0], q1 = bcz2[col1];
        GF4(cA, q0, col0, outB) GF4(cB, q1, col1, outB)
    }
}

// ===== Fused bf16-MFMA scores + masked top-2, v16 =====
// Exact v10 structure (best measured: 47.2 us) + ONE isolated change: the
// segment's candidate descriptors (sdep,sidx) are pre-packed into 3 KB LDS
// once per block, so the per-tile merge is pure LDS+VALU (no L2 loads on the
// post-MFMA dependent path).
#define STG(buf, q, val) { int r_ = (q) >> 4, c_ = (q) & 15; \
    (buf)[r_ * 16 + (c_ ^ (r_ & 7))] = (val); }

#define KC2(kc, AX, AY) { \
    int co_ = (kc) * 4 + quad; \
    int bo_ = bbase + (co_ ^ brm); \
    s8v b0_ = __builtin_bit_cast(s8v, B[bo_      ]); \
    s8v b1_ = __builtin_bit_cast(s8v, B[bo_ + 256]); \
    s8v b2_ = __builtin_bit_cast(s8v, B[bo_ + 512]); \
    s8v b3_ = __builtin_bit_cast(s8v, B[bo_ + 768]); \
    x0 = __builtin_amdgcn_mfma_f32_16x16x32_bf16(AX, b0_, x0, 0, 0, 0); \
    y0 = __builtin_amdgcn_mfma_f32_16x16x32_bf16(AY, b0_, y0, 0, 0, 0); \
    x1 = __builtin_amdgcn_mfma_f32_16x16x32_bf16(AX, b1_, x1, 0, 0, 0); \
    y1 = __builtin_amdgcn_mfma_f32_16x16x32_bf16(AY, b1_, y1, 0, 0, 0); \
    x2 = __builtin_amdgcn_mfma_f32_16x16x32_bf16(AX, b2_, x2, 0, 0, 0); \
    y2 = __builtin_amdgcn_mfma_f32_16x16x32_bf16(AY, b2_, y2, 0, 0, 0); \
    x3 = __builtin_amdgcn_mfma_f32_16x16x32_bf16(AX, b3_, x3, 0, 0, 0); \
    y3 = __builtin_amdgcn_mfma_f32_16x16x32_bf16(AY, b3_, y3, 0, 0, 0); }

// general merge (boundary tiles): per-element depth mask, desc from LDS
#define RMG(K1, K2, EL, DV) { \
    unsigned pb_ = (__builtin_bit_cast(unsigned, EL) & 0xFFFFC000u) | e_; \
    float sf_ = __builtin_bit_cast(float, (du_ < (DV)) ? pb_ : negp_); \
    K2 = __builtin_amdgcn_fmed3f(K1, K2, sf_); \
    K1 = fmaxf(K1, sf_); }

#define MGEN(nb, XA, YA) { \
    unsigned pk_ = eds[ebase + (nb) * 16 + lane16]; \
    int du_ = (int)(pk_ >> 16); \
    unsigned e_ = pk_ & 0x3FFFu; \
    unsigned negp_ = negbase | e_; \
    RMG(k1x0, k2x0, XA[0], dvx0) RMG(k1x1, k2x1, XA[1], dvx1) \
    RMG(k1x2, k2x2, XA[2], dvx2) RMG(k1x3, k2x3, XA[3], dvx3) \
    RMG(k1y0, k2y0, YA[0], dvy0) RMG(k1y1, k2y1, YA[1], dvy1) \
    RMG(k1y2, k2y2, YA[2], dvy2) RMG(k1y3, k2y3, YA[3], dvy3) }

// fast merge (tile fully valid for all 32 rows of the wave): no mask
#define RMF(K1, K2, EL) { \
    float sf_ = __builtin_bit_cast(float, \
        (__builtin_bit_cast(unsigned, EL) & 0xFFFFC000u) | e_); \
    K2 = __builtin_amdgcn_fmed3f(K1, K2, sf_); \
    K1 = fmaxf(K1, sf_); }

#define MFAST(nb, XA, YA) { \
    unsigned e_ = eds[ebase + (nb) * 16 + lane16] & 0x3FFFu; \
    RMF(k1x0, k2x0, XA[0]) RMF(k1x1, k2x1, XA[1]) \
    RMF(k1x2, k2x2, XA[2]) RMF(k1x3, k2x3, XA[3]) \
    RMF(k1y0, k2y0, YA[0]) RMF(k1y1, k2y1, YA[1]) \
    RMF(k1y2, k2y2, YA[2]) RMF(k1y3, k2y3, YA[3]) }

#define BF1(K1, K2, m) { \
    float o1_ = __shfl_xor(K1, m, 64); \
    float o2_ = __shfl_xor(K2, m, 64); \
    float m2_ = fmaxf(K2, o2_); \
    K2 = __builtin_amdgcn_fmed3f(K1, o1_, m2_); \
    K1 = fmaxf(K1, o1_); }

#define BFALL(m) \
    BF1(k1x0, k2x0, m) BF1(k1x1, k2x1, m) BF1(k1x2, k2x2, m) BF1(k1x3, k2x3, m) \
    BF1(k1y0, k2y0, m) BF1(k1y1, k2y1, m) BF1(k1y2, k2y2, m) BF1(k1y3, k2y3, m)

#define EMIT2(K1, K2, GROW) { \
    size_t o = ((size_t)seg * NN + (GROW)) * 2; \
    pv[o] = K1; pv[o + 1] = K2; }

__global__ __launch_bounds__(256) void k_score_top2_mfma(
        const __hip_bfloat16* __restrict__ htb,
        const __hip_bfloat16* __restrict__ hsb,
        const int* __restrict__ sdep, const int* __restrict__ sidx,
        const int* __restrict__ bofs,
        float* __restrict__ pv) {
    __shared__ float4 Bs4[2][64 * 16];   // 32 KB double buffer (B only)
    __shared__ unsigned eds[12 * 64];    // 3 KB packed (depth<<16)|(0x3FFF-sidx)
    int tid = threadIdx.x;
    int w = tid >> 6;
    int l = tid & 63;
    int lane16 = l & 15;
    int quad = l >> 4;
    int rb = (int)gridDim.x - 1 - (int)blockIdx.x;  // heavy blocks first
    int row0 = rb * 128;
    int seg = blockIdx.y;
    const unsigned negbase = __builtin_bit_cast(unsigned, NEGV) & 0xFFFFC000u;

    // balanced split: ns = ceil(nt/12) active segments (<= 16), ~12 tiles ea.
    int dmax = sdep[row0 + 127];
    int lim = bofs[dmax];
    int nt = (lim + 63) >> 6;               // total tiles, <= 192
    int ns = (nt + 11) / 12;
    if (ns < 1) ns = 1;
    if (seg >= ns) {
        if (tid < 128) {
            int grow = sidx[row0 + tid];
            size_t o = ((size_t)seg * NN + grow) * 2;
            pv[o]     = __builtin_bit_cast(float, negbase | 0x3FFFu);
            pv[o + 1] = __builtin_bit_cast(float, negbase | 0x3FFEu);
        }
        return;
    }
    int t0 = (seg * nt) / ns;
    int t1 = ((seg + 1) * nt) / ns;

    // A fragments: 32 sorted target rows per wave, two 16-row MFMA groups.
    int rbase = row0 + w * 32;
    s8v ax0, ax1, ax2, ax3, ay0, ay1, ay2, ay3;
    {
        const float4* gx = (const float4*)(htb + (size_t)(rbase + lane16) * HD);
        ax0 = __builtin_bit_cast(s8v, gx[quad]);
        ax1 = __builtin_bit_cast(s8v, gx[4 + quad]);
        ax2 = __builtin_bit_cast(s8v, gx[8 + quad]);
        ax3 = __builtin_bit_cast(s8v, gx[12 + quad]);
        const float4* gy = (const float4*)(htb + (size_t)(rbase + 16 + lane16) * HD);
        ay0 = __builtin_bit_cast(s8v, gy[quad]);
        ay1 = __builtin_bit_cast(s8v, gy[4 + quad]);
        ay2 = __builtin_bit_cast(s8v, gy[8 + quad]);
        ay3 = __builtin_bit_cast(s8v, gy[12 + quad]);
    }
    // pack candidate descriptors for the whole segment into LDS (once);
    // consumed only after the first loop-top barrier.
    for (int i = tid; i < (t1 - t0) * 64; i += 256) {
        int p = t0 * 64 + i;
        eds[i] = ((unsigned)sdep[p] << 16) | (0x3FFFu - (unsigned)sidx[p]);
    }
    if (t0 < t1) {   // stage first tile into the parity-matching buffer
        float4* B0 = Bs4[t0 & 1];
        const float4* gb = (const float4*)(hsb + (size_t)(t0 * 64) * HD);
        float4 b0_ = gb[tid], b1_ = gb[tid + 256], b2_ = gb[tid + 512], b3_ = gb[tid + 768];
        STG(B0, tid, b0_) STG(B0, tid + 256, b1_)
        STG(B0, tid + 512, b2_) STG(B0, tid + 768, b3_)
    }

    int bbase = lane16 * 16, brm = lane16 & 7;

    int dvx0 = sdep[rbase + quad * 4 + 0];
    int dvx1 = sdep[rbase + quad * 4 + 1];
    int dvx2 = sdep[rbase + quad * 4 + 2];
    int dvx3 = sdep[rbase + quad * 4 + 3];
    int dvy0 = sdep[rbase + 16 + quad * 4 + 0];
    int dvy1 = sdep[rbase + 16 + quad * 4 + 1];
    int dvy2 = sdep[rbase + 16 + quad * 4 + 2];
    int dvy3 = sdep[rbase + 16 + quad * 4 + 3];
    // wave window: cands < lim_lo valid for EVERY row; >= lim_hi for none.
    int lim_lo = bofs[sdep[rbase]];
    int lim_hi = bofs[sdep[rbase + 31]];

    // defaults: packed NEGV for orig u=0 (k1) and u=1 (k2), lane16==0 only.
    float ki1 = (lane16 == 0) ? __builtin_bit_cast(float, negbase | 0x3FFFu) : -3.4e38f;
    float ki2 = (lane16 == 0) ? __builtin_bit_cast(float, negbase | 0x3FFEu) : -3.4e38f;
    float k1x0 = ki1, k1x1 = ki1, k1x2 = ki1, k1x3 = ki1;
    float k1y0 = ki1, k1y1 = ki1, k1y2 = ki1, k1y3 = ki1;
    float k2x0 = ki2, k2x1 = ki2, k2x2 = ki2, k2x3 = ki2;
    float k2y0 = ki2, k2y1 = ki2, k2y2 = ki2, k2y3 = ki2;

    float4 p0, p1, p2, p3;
    for (int t = t0; t < t1; ++t) {
        int u0 = t * 64;
        int ebase = (t - t0) * 64;
        __syncthreads();
        if (t + 1 < t1) {
            const float4* g = (const float4*)(hsb + (size_t)(u0 + 64) * HD);
            p0 = g[tid]; p1 = g[tid + 256]; p2 = g[tid + 512]; p3 = g[tid + 768];
        }
        if (u0 < lim_hi) {          // wave-uniform: tile matters for >=1 row
            const float4* B = Bs4[t & 1];
            f4v x0 = (f4v){0.f, 0.f, 0.f, 0.f};
            f4v x1 = (f4v){0.f, 0.f, 0.f, 0.f};
            f4v x2 = (f4v){0.f, 0.f, 0.f, 0.f};
            f4v x3 = (f4v){0.f, 0.f, 0.f, 0.f};
            f4v y0 = (f4v){0.f, 0.f, 0.f, 0.f};
            f4v y1 = (f4v){0.f, 0.f, 0.f, 0.f};
            f4v y2 = (f4v){0.f, 0.f, 0.f, 0.f};
            f4v y3 = (f4v){0.f, 0.f, 0.f, 0.f};
            KC2(0, ax0, ay0) KC2(1, ax1, ay1) KC2(2, ax2, ay2) KC2(3, ax3, ay3)
            if (u0 + 64 <= lim_lo) {   // fully valid for all 32 rows
                MFAST(0, x0, y0) MFAST(1, x1, y1)
                MFAST(2, x2, y2) MFAST(3, x3, y3)
            } else {                   // boundary: per-element depth mask
                MGEN(0, x0, y0) MGEN(1, x1, y1)
                MGEN(2, x2, y2) MGEN(3, x3, y3)
            }
        }
        if (t + 1 < t1) {
            float4* Bn = Bs4[(t + 1) & 1];
            STG(Bn, tid, p0) STG(Bn, tid + 256, p1)
            STG(Bn, tid + 512, p2) STG(Bn, tid + 768, p3)
        }
    }

    BFALL(1) BFALL(2) BFALL(4) BFALL(8)

    if (lane16 == 0) {
        int gbse = rbase + quad * 4;
        EMIT2(k1x0, k2x0, sidx[gbse + 0])
        EMIT2(k1x1, k2x1, sidx[gbse + 1])
        EMIT2(k1x2, k2x2, sidx[gbse + 2])
        EMIT2(k1x3, k2x3, sidx[gbse + 3])
        EMIT2(k1y0, k2y0, sidx[gbse + 16])
        EMIT2(k1y1, k2y1, sidx[gbse + 17])
        EMIT2(k1y2, k2y2, sidx[gbse + 18])
        EMIT2(k1y3, k2y3, sidx[gbse + 19])
    }
}

// ONE kernel writes ALL outputs (f32): parallel packed merge (r15-proven).
__global__ __launch_bounds__(256) void k_final(const float* __restrict__ pv,
                                               const int* __restrict__ ntype,
                                               const int* __restrict__ ndepth,
                                               const float* __restrict__ A,
                                               const float* __restrict__ B,
                                               const float* __restrict__ Wi2,
                                               const float* __restrict__ bi2,
                                               float* __restrict__ out) {
    int tid = threadIdx.x;
    int lane = tid & 63;
    int v = blockIdx.x * 4 + (tid >> 6);

    float k1 = -3.4e38f;
    if (lane < 32) {
        k1 = pv[((size_t)(lane >> 1) * NN + v) * 2 + (lane & 1)];
    }
    float k2 = -3.4e38f;
#pragma unroll
    for (int m = 1; m <= 16; m <<= 1) {
        float o1 = __shfl_xor(k1, m, 64);
        float o2 = __shfl_xor(k2, m, 64);
        float m2 = fmaxf(k2, o2);
        k2 = __builtin_amdgcn_fmed3f(k1, o1, m2);
        k1 = fmaxf(k1, o1);
    }
    float K1 = __shfl(k1, 0, 64);
    float K2 = __shfl(k2, 0, 64);
    unsigned b1 = __builtin_bit_cast(unsigned, K1);
    unsigned b2 = __builtin_bit_cast(unsigned, K2);
    int I1 = 0x3FFF - (int)(b1 & 0x3FFFu);
    int I2 = 0x3FFF - (int)(b2 & 0x3FFFu);

    if (lane == 0) {
        int tp = ntype[v];
        bool tv = (tp != 0) && (ndepth[v] > 0) && (K1 > -5.0e8f);  // NEG/2
        out[2 * NN + 2 * v]     = K1;
        out[2 * NN + 2 * v + 1] = K2;
        out[4 * NN + 2 * v]     = (float)I1;
        out[4 * NN + 2 * v + 1] = (float)I2;
        out[6 * NN + 2 * v]     = tv ? 1.f : 0.f;
        out[6 * NN + 2 * v + 1] = (tv && tp == 2) ? 1.f : 0.f;
    }

    int u1 = min(max(I1, 0), NN - 1);
    int u2 = min(max(I2, 0), NN - 1);
    const float2* A2p = (const float2*)A;
    float2 av1 = A2p[(size_t)u1 * 64 + lane];
    float2 av2 = A2p[(size_t)u2 * 64 + lane];
    float2 bv = ((const float2*)B)[(size_t)v * 64 + lane];
    float2 wv = ((const float2*)Wi2)[lane];
    float bias = bi2[0];
    float a1 = fmaf(fmaxf(av1.x + bv.x, 0.f), wv.x,
                    fmaxf(av1.y + bv.y, 0.f) * wv.y);
    float a2 = fmaf(fmaxf(av2.x + bv.x, 0.f), wv.x,
                    fmaxf(av2.y + bv.y, 0.f) * wv.y);
#pragma unroll
    for (int off = 32; off > 0; off >>= 1) {
        a1 += __shfl_down(a1, off);
        a2 += __shfl_down(a2, off);
    }
    if (lane == 0) {
        out[2 * v]     = 1.f / (1.f + expf(-(a1 + bias)));
        out[2 * v + 1] = 1.f / (1.f + expf(-(a2 + bias)));
    }
}

extern "C" void kernel_launch(void* const* d_in, const int* in_sizes, int n_in,
                              void* d_out, int out_size, void* d_ws, size_t ws_size,
                              hipStream_t stream) {
    (void)in_sizes; (void)n_in; (void)out_size; (void)ws_size;
    const float* x   = (const float*)d_in[0];
    const float* z   = (const float*)d_in[1];
    const int* ntype = (const int*)d_in[2];
    const int* ndep  = (const int*)d_in[3];
    const int* eidx  = (const int*)d_in[4];
    const float* W1  = (const float*)d_in[5];
    const float* b1  = (const float*)d_in[6];
    const float* W2  = (const float*)d_in[7];
    const float* b2  = (const float*)d_in[8];
    const float* Wm1 = (const float*)d_in[9];
    const float* bm1 = (const float*)d_in[10];
    const float* Wm2 = (const float*)d_in[11];
    const float* bm2 = (const float*)d_in[12];
    const float* Wsm = (const float*)d_in[13];
    const float* Wtm = (const float*)d_in[14];
    const float* Wi1 = (const float*)d_in[15];
    const float* bi1 = (const float*)d_in[16];
    const float* Wi2 = (const float*)d_in[17];
    const float* bi2 = (const float*)d_in[18];
    float* out = (float*)d_out;

    const int* esrc = eidx;
    const int* edst = eidx + NE;

    // Workspace layout (~24.5 MiB). The pi spacer (unused S2N ints) hosts
    // the line-padded cnt/dcur counters (stride 16 -> 1 counter per 64B line).
    const size_t S2N = (size_t)SEG * 2 * NN;  // 393216
    float* ws = (float*)d_ws;
    float* pv     = ws;                       // [S2N] f (packed scores)
    int*   pi     = (int*)(pv + S2N);         // [S2N] i (spacer)
    int*   cnt    = pi;                       // [64*16] padded depth counts
    int*   dcur   = pi + 1024;                // [64*16] padded depth cursors
    int*   degi   = pi + S2N;                 // [NN]   (memset)
    float* inv    = (float*)(degi + NN + 64); // [NN]  (old cnt slot = pad)
    float* agg2   = inv + NN;                 // [2NN]
    float* cz1    = agg2 + 2 * NN;            // [128]
    float* cz2    = cz1 + 128;                // [128]
    int*   offs   = (int*)(cz2 + 128);        // [NN+16]
    int*   cursor = offs + NN + 16;           // [NN]
    int*   bofs   = cursor + NN;              // [80]
    int*   sidx   = bofs + 80 + 64;           // [NN] (old dcur slot = pad)
    int*   sdep   = sidx + NN;                // [NN]
    int*   prank  = sdep + NN;                // [NN]
    int*   ebsrc  = prank + NN;               // [NE]
    float* ebw    = (float*)(ebsrc + NE);     // [NE]
    __hip_bfloat16* wt7 = (__hip_bfloat16*)(ebw + NE);  // [7*16384] bf16
    size_t F = (size_t)NN * HD;
    float* s0 = (float*)(wt7 + 7 * 16384);    // h1b (bf16) -> {htb_s, hsb_s}
    float* s1 = s0 + F;                       // aggH -> B (in-place)
    float* s2 = s1 + F;                       // A
    unsigned short* h1b = (unsigned short*)s0;
    __hip_bfloat16* htb = (__hip_bfloat16*)s0;
    __hip_bfloat16* hsb = htb + F;

    hipMemsetAsync(degi, 0, NN * sizeof(int), stream);
    hipMemsetAsync(cnt, 0, 1024 * sizeof(int), stream);
    k_counts_wz<<<NE / 256 + NN / 256 + 448 + 1, 256, 0, stream>>>(
        edst, ndep, W2, Wm1, Wm2, Wtm, Wsm, Wi1, z, bm1, bi1,
        degi, cnt, wt7, cz1, cz2);
    k_prefix<<<1, 1024, 0, stream>>>(degi, cnt, x, inv, agg2, offs, cursor, bofs, dcur);
    k_bucket_scatter<<<NE / 256 + NN / 256, 256, 0, stream>>>(
        esrc, edst, ndep, inv, cursor, ebsrc, ebw, dcur, sidx, sdep, prank);
    k_gl1<<<NN / 32, 256, 0, stream>>>(offs, ebsrc, ebw, x, agg2, W1, b1, inv,
                                       h1b, s1);
    k_gatherH<<<NN / 4, 256, 0, stream>>>(offs, ebsrc, ebw, h1b, s1);
    k_mlp7_mfma<<<NN / 16, 256, 0, stream>>>(s1, wt7, b2, cz1, bm2, cz2,
                                             prank, s2, s1, htb, hsb);
    k_score_top2_mfma<<<dim3(NN / 128, SEG), 256, 0, stream>>>(
        htb, hsb, sdep, sidx, bofs, pv);
    k_final<<<NN / 4, 256, 0, stream>>>(pv, ntype, ndep, s2, s1, Wi2, bi2, out);
}

// Round 9
// 224.816 us; speedup vs baseline: 1.0441x; 1.0033x over previous
//
#include <hip/hip_runtime.h>
#include <hip/hip_bf16.h>

#define NN 12288
#define NE 196608
#define HD 128
#define ZD 128
#define NEGV (-1.0e9f)
#define SEG 16

using s8v = __attribute__((ext_vector_type(8))) short;  // 8 bf16 = 4 VGPRs
using f4v = __attribute__((ext_vector_type(4))) float;  // 4 fp32 acc
using i4v = __attribute__((ext_vector_type(4))) int;

__device__ __forceinline__ unsigned short f2bf(float f) {
    return __builtin_bit_cast(unsigned short, __float2bfloat16(f));
}
__device__ __forceinline__ float4 pack8(float4 a, float4 b) {
    unsigned p0 = ((unsigned)f2bf(a.y) << 16) | f2bf(a.x);
    unsigned p1 = ((unsigned)f2bf(a.w) << 16) | f2bf(a.z);
    unsigned p2 = ((unsigned)f2bf(b.y) << 16) | f2bf(b.x);
    unsigned p3 = ((unsigned)f2bf(b.w) << 16) | f2bf(b.z);
    i4v r = (i4v){(int)p0, (int)p1, (int)p2, (int)p3};
    return __builtin_bit_cast(float4, r);
}

// Mega split-grid of INDEPENDENT prep work:
// [0,768): edge in-degree count; [768,816): depth-bucket count (LDS hist ->
// line-padded counters); [816,872): 7x weight transpose via LDS tiles
// (v17: coalesced — old version did 114K scattered 2B stores); [872]: cz1/cz2.
__global__ __launch_bounds__(256) void k_counts_wz(
        const int* __restrict__ edst, const int* __restrict__ ndep,
        const float* __restrict__ W2, const float* __restrict__ Wm1,
        const float* __restrict__ Wm2, const float* __restrict__ Wtm,
        const float* __restrict__ Wsm, const float* __restrict__ Wi1,
        const float* __restrict__ z, const float* __restrict__ bm1,
        const float* __restrict__ bi1,
        int* degi, int* cnt, __hip_bfloat16* __restrict__ wt7,
        float* cz1, float* cz2) {
    __shared__ int lh[64];
    __shared__ float tl[16 * 129];   // padded transpose tile (8.25 KB)
    int tid = threadIdx.x;
    int bid = blockIdx.x;
    if (bid < NE / 256) {
        int e = bid * 256 + tid;
        atomicAdd(&degi[edst[e]], 1);
    } else if (bid < NE / 256 + NN / 256) {
        // depth histogram: LDS-aggregate, then 1 global atomic per depth per
        // block onto stride-16 (one-per-cacheline) counters.
        if (tid < 64) lh[tid] = 0;
        __syncthreads();
        int v = (bid - NE / 256) * 256 + tid;
        atomicAdd(&lh[ndep[v]], 1);
        __syncthreads();
        if (tid < 64) {
            int c = lh[tid];
            if (c) atomicAdd(&cnt[tid * 16], c);
        }
    } else if (bid < NE / 256 + NN / 256 + 56) {
        // weight transpose: one block = one 16(k)x128(n) slice of one matrix.
        int b2 = bid - NE / 256 - NN / 256;   // 0..55
        int g = b2 >> 3;
        int k0 = (b2 & 7) << 4;
        const float* src;
        if (g == 0) src = W2;
        else if (g == 1) src = Wm1;
        else if (g == 2) src = Wm2;
        else if (g == 3) src = Wtm;
        else if (g == 4) src = Wsm;
        else if (g == 5) src = Wi1;
        else src = Wi1 + 128 * HD;
#pragma unroll
        for (int i = 0; i < 8; ++i) {         // coalesced f32 reads
            int idx = i * 256 + tid;
            int kk = idx >> 7, n = idx & 127;
            tl[kk * 129 + n] = src[(k0 + kk) * 128 + n];
        }
        __syncthreads();
#pragma unroll
        for (int i = 0; i < 8; ++i) {         // 32B-run bf16 writes
            int idx = i * 256 + tid;
            int n = idx >> 4, kk = idx & 15;
            wt7[(g << 14) + n * 128 + k0 + kk] = __float2bfloat16(tl[kk * 129 + n]);
        }
    } else {
        int j = tid & 127;
        const float* W = (tid < 128) ? (Wm1 + HD * HD) : (Wi1 + 2 * HD * HD);
        float A0 = 0.f, A1 = 0.f, A2 = 0.f, A3 = 0.f;
        for (int k = 0; k < ZD; k += 4) {
            A0 = fmaf(z[k],     W[(k    ) * HD + j], A0);
            A1 = fmaf(z[k + 1], W[(k + 1) * HD + j], A1);
            A2 = fmaf(z[k + 2], W[(k + 2) * HD + j], A2);
            A3 = fmaf(z[k + 3], W[(k + 3) * HD + j], A3);
        }
        float r = (A0 + A1) + (A2 + A3);
        if (tid < 128) cz1[j] = r + bm1[j];
        else           cz2[j] = r + bi1[j];
    }
}

// ONE block, 1024 threads: CSR offsets (+cursor), inv = rsqrt(deg+1), agg2
// self term, xi = (x.x, x.y, inv, 0) packed float4, plus (tid 0) the
// 64-bucket depth scan -> bofs/dcur.
__global__ __launch_bounds__(1024) void k_prefix(const int* __restrict__ degi,
                                                 const int* __restrict__ cnt,
                                                 const float* __restrict__ x,
                                                 float* inv, float* agg2,
                                                 float4* __restrict__ xi,
                                                 int* offs, int* cursor,
                                                 int* bofs, int* dcur) {
    __shared__ int ldeg[NN];     // 48 KB: degi, then overwritten by prefix
    __shared__ int part[1024];   // 4 KB
    __shared__ int stot;
    int tid = threadIdx.x;
#pragma unroll
    for (int k = 0; k < 12; ++k)          // coalesced: lane-stride 4B
        ldeg[k * 1024 + tid] = degi[k * 1024 + tid];
    __syncthreads();
    int base = tid * 12;
    int s = 0;
#pragma unroll
    for (int k = 0; k < 12; ++k) s += ldeg[base + k];
    part[tid] = s;
    __syncthreads();
    for (int off = 1; off < 1024; off <<= 1) {
        int v = (tid >= off) ? part[tid - off] : 0;
        __syncthreads();
        part[tid] += v;
        __syncthreads();
    }
    int run = part[tid] - s;  // exclusive base for this thread's 12 elems
#pragma unroll
    for (int k = 0; k < 12; ++k) {        // overwrite LDS with excl prefix
        int d = ldeg[base + k];
        ldeg[base + k] = run;
        run += d;
    }
    if (tid == 1023) stot = run;          // grand total
    __syncthreads();
    int total = stot;
    const float2* X2 = (const float2*)x;
    float2* A2 = (float2*)agg2;
#pragma unroll
    for (int k = 0; k < 12; ++k) {        // coalesced output phase
        int i = k * 1024 + tid;
        int p = ldeg[i];
        int nxt = (i < NN - 1) ? ldeg[i + 1] : total;
        int d = nxt - p;                  // recover degree
        offs[i] = p;
        cursor[i] = p;
        float iv = rsqrtf((float)(d + 1));
        inv[i] = iv;
        float w = iv * iv;
        float2 xv = X2[i];
        float2 av; av.x = xv.x * w; av.y = xv.y * w;
        A2[i] = av;
        float4 xo; xo.x = xv.x; xo.y = xv.y; xo.z = iv; xo.w = 0.f;
        xi[i] = xo;
    }
    if (tid == 0) {
        offs[NN] = total;
        int r = 0;                        // depth-bucket exclusive scan
        for (int d = 0; d < 64; ++d) {
            bofs[d] = r;
            dcur[d * 16] = r;
            r += cnt[d * 16];
        }
        bofs[64] = r;
    }
}

// Split grid: blocks [0,768) bucket edges (v17: ebsrc only — no ebw, no
// random inv reads; normalization is separable and applied in the gather
// kernels); [768,816) depth-sort scatter (LDS local-rank + padded atomics).
__global__ __launch_bounds__(256) void k_bucket_scatter(
        const int* __restrict__ esrc, const int* __restrict__ edst,
        const int* __restrict__ ndep,
        int* cursor, int* ebsrc,
        int* dcur, int* sidx, int* sdep, int* prank) {
    __shared__ int lh[64];
    __shared__ int lbase[64];
    int tid = threadIdx.x;
    if (blockIdx.x < NE / 256) {
        int e = blockIdx.x * 256 + tid;
        int u = esrc[e], v = edst[e];
        int pos = atomicAdd(&cursor[v], 1);
        ebsrc[pos] = u;
    } else {
        if (tid < 64) lh[tid] = 0;
        __syncthreads();
        int v = (blockIdx.x - NE / 256) * 256 + tid;
        int d = ndep[v];
        int r = atomicAdd(&lh[d], 1);          // local rank within block
        __syncthreads();
        if (tid < 64) {
            int c = lh[tid];
            if (c) lbase[tid] = atomicAdd(&dcur[tid * 16], c);
        }
        __syncthreads();
        int p = lbase[d] + r;
        sidx[p] = v;
        sdep[p] = d;
        prank[v] = p;
    }
}

// FUSED layer-1 gather + lin1. Phase 1: 8 lanes/node accumulate
// inv[u]*x[u] from ONE aligned 16B xi load per edge; scale by inv[v] once.
// Phase 2: h1c = relu(agg @ W1 + b1) * inv[v] (bf16, pre-scaled for the
// separable layer-2 normalization) and aggH self-loop seed.
__global__ __launch_bounds__(256) void k_gl1(const int* __restrict__ offs,
                                             const int* __restrict__ ebsrc,
                                             const float4* __restrict__ xi,
                                             const float* __restrict__ agg2,
                                             const float* __restrict__ W1,
                                             const float* __restrict__ b1,
                                             const float* __restrict__ inv,
                                             unsigned short* h1b, float* aggH) {
    __shared__ float2 la[32];
    int tid = threadIdx.x;
    int v0 = blockIdx.x * 32;
    {   // phase 1: edge gather, 8 lanes/node
        int nb = tid >> 3;
        int sl = tid & 7;
        int v = v0 + nb;
        int b = offs[v], e = offs[v + 1];
        float ax = 0.f, ay = 0.f;
        for (int k = b + sl; k < e; k += 8) {
            int u = ebsrc[k];
            float4 xv = xi[u];                 // (x0, x1, inv_u, 0)
            ax = fmaf(xv.x, xv.z, ax);
            ay = fmaf(xv.y, xv.z, ay);
        }
#pragma unroll
        for (int m = 1; m < 8; m <<= 1) {   // 8-lane groups are lane-aligned
            ax += __shfl_xor(ax, m, 64);
            ay += __shfl_xor(ay, m, 64);
        }
        if (sl == 0) {
            float ivv = inv[v];
            float2 seed = ((const float2*)agg2)[v];  // self term (k_prefix)
            seed.x = fmaf(ax, ivv, seed.x);
            seed.y = fmaf(ay, ivv, seed.y);
            la[nb] = seed;
        }
    }
    __syncthreads();
    {   // phase 2: 32 nodes x 128 cols = 4096 outputs, 16 per thread
#pragma unroll
        for (int k = 0; k < 16; ++k) {
            int idx = k * 256 + tid;
            int vloc = idx >> 7, j = idx & 127;
            float2 a = la[vloc];
            float hv = fmaxf(fmaf(a.x, W1[j], fmaf(a.y, W1[HD + j], b1[j])), 0.f);
            int t = (v0 + vloc) * HD + j;
            float iv = inv[v0 + vloc];
            h1b[t] = f2bf(hv * iv);            // pre-scaled h1c
            aggH[t] = hv * iv * iv;            // self-loop seed (exact f32)
        }
    }
}

// Layer-2 aggregation: one WAVE per node; h1c rows are pre-scaled by inv[u],
// so acc needs no per-edge weight; scale by inv[v] once at the end.
__global__ __launch_bounds__(256) void k_gatherH(const int* __restrict__ offs,
                                                 const int* __restrict__ ebsrc,
                                                 const float* __restrict__ inv,
                                                 const unsigned short* __restrict__ h1b,
                                                 float* aggH) {
    int tid = threadIdx.x;
    int lane = tid & 63;
    int v = blockIdx.x * 4 + (tid >> 6);
    const unsigned* H1 = (const unsigned*)h1b;
    float2* A2 = (float2*)aggH;
    float2 acc; acc.x = 0.f; acc.y = 0.f;
    int b = offs[v], e = offs[v + 1];
    int k = b;
    for (; k + 4 <= e; k += 4) {
        int u0 = ebsrc[k], u1 = ebsrc[k + 1], u2 = ebsrc[k + 2], u3 = ebsrc[k + 3];
        unsigned hb0 = H1[(size_t)u0 * 64 + lane];
        unsigned hb1 = H1[(size_t)u1 * 64 + lane];
        unsigned hb2 = H1[(size_t)u2 * 64 + lane];
        unsigned hb3 = H1[(size_t)u3 * 64 + lane];
        acc.x += __builtin_bit_cast(float, hb0 << 16);
        acc.y += __builtin_bit_cast(float, hb0 & 0xFFFF0000u);
        acc.x += __builtin_bit_cast(float, hb1 << 16);
        acc.y += __builtin_bit_cast(float, hb1 & 0xFFFF0000u);
        acc.x += __builtin_bit_cast(float, hb2 << 16);
        acc.y += __builtin_bit_cast(float, hb2 & 0xFFFF0000u);
        acc.x += __builtin_bit_cast(float, hb3 << 16);
        acc.y += __builtin_bit_cast(float, hb3 & 0xFFFF0000u);
    }
    for (; k < e; ++k) {
        int u = ebsrc[k];
        unsigned hb = H1[(size_t)u * 64 + lane];
        acc.x += __builtin_bit_cast(float, hb << 16);
        acc.y += __builtin_bit_cast(float, hb & 0xFFFF0000u);
    }
    float ivv = inv[v];
    float2 seed = A2[(size_t)v * 64 + lane];
    seed.x = fmaf(acc.x, ivv, seed.x);
    seed.y = fmaf(acc.y, ivv, seed.y);
    A2[(size_t)v * 64 + lane] = seed;
}

// ===== Fused 7-GEMM MLP chain on MFMA (r10-proven; ht/hs scatter to sorted
// row positions via prank) =====
#define AFRAGS(BUF) \
    s8v a0_ = __builtin_bit_cast(s8v, (BUF)[lane16 * 16 + ((quad     ) ^ lane16)]); \
    s8v a1_ = __builtin_bit_cast(s8v, (BUF)[lane16 * 16 + ((quad +  4) ^ lane16)]); \
    s8v a2_ = __builtin_bit_cast(s8v, (BUF)[lane16 * 16 + ((quad +  8) ^ lane16)]); \
    s8v a3_ = __builtin_bit_cast(s8v, (BUF)[lane16 * 16 + ((quad + 12) ^ lane16)]);

#define NBACC(WT4, NCOL, ACC) \
    f4v ACC = (f4v){0.f, 0.f, 0.f, 0.f}; \
    ACC = __builtin_amdgcn_mfma_f32_16x16x32_bf16(a0_, __builtin_bit_cast(s8v, (WT4)[(NCOL) * 16 + quad     ]), ACC, 0, 0, 0); \
    ACC = __builtin_amdgcn_mfma_f32_16x16x32_bf16(a1_, __builtin_bit_cast(s8v, (WT4)[(NCOL) * 16 + quad +  4]), ACC, 0, 0, 0); \
    ACC = __builtin_amdgcn_mfma_f32_16x16x32_bf16(a2_, __builtin_bit_cast(s8v, (WT4)[(NCOL) * 16 + quad +  8]), ACC, 0, 0, 0); \
    ACC = __builtin_amdgcn_mfma_f32_16x16x32_bf16(a3_, __builtin_bit_cast(s8v, (WT4)[(NCOL) * 16 + quad + 12]), ACC, 0, 0, 0);

#define BST(EXPR, RR, COL, USPTR) { int rw_ = quad * 4 + (RR); int cc_ = (COL) >> 3; \
    (USPTR)[rw_ * 128 + (((cc_ ^ rw_)) << 3) + ((COL) & 7)] = f2bf(EXPR); }

#define LDS4R(ACC, B, COL, US) \
    BST(fmaxf(ACC[0] + (B), 0.f), 0, COL, US) BST(fmaxf(ACC[1] + (B), 0.f), 1, COL, US) \
    BST(fmaxf(ACC[2] + (B), 0.f), 2, COL, US) BST(fmaxf(ACC[3] + (B), 0.f), 3, COL, US)

#define LDS4(ACC, B, COL, US) \
    BST(ACC[0] + (B), 0, COL, US) BST(ACC[1] + (B), 1, COL, US) \
    BST(ACC[2] + (B), 2, COL, US) BST(ACC[3] + (B), 3, COL, US)

#define GBF4S(ACC, COL, PTR) \
    ((unsigned short*)(PTR))[(size_t)pr0 * HD + (COL)] = f2bf(ACC[0]); \
    ((unsigned short*)(PTR))[(size_t)pr1 * HD + (COL)] = f2bf(ACC[1]); \
    ((unsigned short*)(PTR))[(size_t)pr2 * HD + (COL)] = f2bf(ACC[2]); \
    ((unsigned short*)(PTR))[(size_t)pr3 * HD + (COL)] = f2bf(ACC[3]);

#define GF4(ACC, B, COL, PTR) \
    (PTR)[(size_t)(r0 + quad * 4 + 0) * HD + (COL)] = ACC[0] + (B); \
    (PTR)[(size_t)(r0 + quad * 4 + 1) * HD + (COL)] = ACC[1] + (B); \
    (PTR)[(size_t)(r0 + quad * 4 + 2) * HD + (COL)] = ACC[2] + (B); \
    (PTR)[(size_t)(r0 + quad * 4 + 3) * HD + (COL)] = ACC[3] + (B);

__global__ __launch_bounds__(256) void k_mlp7_mfma(
        const float* __restrict__ s1in, const __hip_bfloat16* __restrict__ wt7,
        const float* __restrict__ bb2, const float* __restrict__ bcz1,
        const float* __restrict__ bbm2, const float* __restrict__ bcz2,
        const int* __restrict__ prank,
        float* __restrict__ outA, float* __restrict__ outB,
        __hip_bfloat16* __restrict__ htb, __hip_bfloat16* __restrict__ hsb) {
    __shared__ float4 bufA4[256];  // 16 rows x 16 chunks (bf16x8) = 4 KB
    __shared__ float4 bufB4[256];
    int tid = threadIdx.x;
    int wv = tid >> 6;
    int l = tid & 63;
    int lane16 = l & 15;
    int quad = l >> 4;
    int r0 = blockIdx.x * 16;
    const float4* wt4 = (const float4*)wt7;

    int pr0 = prank[r0 + quad * 4 + 0];
    int pr1 = prank[r0 + quad * 4 + 1];
    int pr2 = prank[r0 + quad * 4 + 2];
    int pr3 = prank[r0 + quad * 4 + 3];

    {
        const float4* g4 = (const float4*)(s1in + (size_t)r0 * HD);
        float4 u0 = g4[2 * tid], u1 = g4[2 * tid + 1];
        int row_ = tid >> 4, c_ = tid & 15;
        bufA4[row_ * 16 + (c_ ^ row_)] = pack8(u0, u1);
    }
    __syncthreads();
    int col0 = wv * 32 + lane16, col1 = col0 + 16;
    unsigned short* usA = (unsigned short*)bufA4;
    unsigned short* usB = (unsigned short*)bufB4;

    {   // G1: h2 = relu(aggH @ W2 + b2) -> bufB
        AFRAGS(bufA4)
        NBACC(wt4, col0, cA) NBACC(wt4, col1, cB)
        float q0 = bb2[col0], q1 = bb2[col1];
        LDS4R(cA, q0, col0, usB) LDS4R(cB, q1, col1, usB)
    }
    __syncthreads();
    {   // G2: t = relu(h2 @ Wm1 + cz1) -> bufA
        AFRAGS(bufB4)
        const float4* wt = wt4 + 2048;
        NBACC(wt, col0, cA) NBACC(wt, col1, cB)
        float q0 = bcz1[col0], q1 = bcz1[col1];
        LDS4R(cA, q0, col0, usA) LDS4R(cB, q1, col1, usA)
    }
    __syncthreads();
    {   // G3: h = t @ Wm2 + bm2 -> bufB
        AFRAGS(bufA4)
        const float4* wt = wt4 + 2 * 2048;
        NBACC(wt, col0, cA) NBACC(wt, col1, cB)
        float q0 = bbm2[col0], q1 = bbm2[col1];
        LDS4(cA, q0, col0, usB) LDS4(cB, q1, col1, usB)
    }
    __syncthreads();
    {   // G4: ht = h @ Wtm -> sorted rows, bf16
        AFRAGS(bufB4)
        const float4* wt = wt4 + 3 * 2048;
        NBACC(wt, col0, cA) NBACC(wt, col1, cB)
        GBF4S(cA, col0, htb) GBF4S(cB, col1, htb)
    }
    {   // G5: hs = h @ Wsm -> sorted rows, bf16
        AFRAGS(bufB4)
        const float4* wt = wt4 + 4 * 2048;
        NBACC(wt, col0, cA) NBACC(wt, col1, cB)
        GBF4S(cA, col0, hsb) GBF4S(cB, col1, hsb)
    }
    {   // G6: A = h @ Wi1[:128] -> global f32 (original order)
        AFRAGS(bufB4)
        const float4* wt = wt4 + 5 * 2048;
        NBACC(wt, col0, cA) NBACC(wt, col1, cB)
        GF4(cA, 0.f, col0, outA) GF4(cB, 0.f, col1, outA)
    }
    {   // G7: B = h @ Wi1[128:256] + cz2 -> global f32 (in-place over s1)
        AFRAGS(bufB4)
        const float4* wt = wt4 + 6 * 2048;
        NBACC(wt, col0, cA) NBACC(wt, col1, cB)
        float q0 = bcz2[col0], q1 = bcz2[col1];
        GF4(cA, q0, col0, outB) GF4(cB, q1, col1, outB)
    }
}

// ===== Fused bf16-MFMA scores + masked top-2, v16 (best measured 46.3 us) =====
#define STG(buf, q, val) { int r_ = (q) >> 4, c_ = (q) & 15; \
    (buf)[r_ * 16 + (c_ ^ (r_ & 7))] = (val); }

#define KC2(kc, AX, AY) { \
    int co_ = (kc) * 4 + quad; \
    int bo_ = bbase + (co_ ^ brm); \
    s8v b0_ = __builtin_bit_cast(s8v, B[bo_      ]); \
    s8v b1_ = __builtin_bit_cast(s8v, B[bo_ + 256]); \
    s8v b2_ = __builtin_bit_cast(s8v, B[bo_ + 512]); \
    s8v b3_ = __builtin_bit_cast(s8v, B[bo_ + 768]); \
    x0 = __builtin_amdgcn_mfma_f32_16x16x32_bf16(AX, b0_, x0, 0, 0, 0); \
    y0 = __builtin_amdgcn_mfma_f32_16x16x32_bf16(AY, b0_, y0, 0, 0, 0); \
    x1 = __builtin_amdgcn_mfma_f32_16x16x32_bf16(AX, b1_, x1, 0, 0, 0); \
    y1 = __builtin_amdgcn_mfma_f32_16x16x32_bf16(AY, b1_, y1, 0, 0, 0); \
    x2 = __builtin_amdgcn_mfma_f32_16x16x32_bf16(AX, b2_, x2, 0, 0, 0); \
    y2 = __builtin_amdgcn_mfma_f32_16x16x32_bf16(AY, b2_, y2, 0, 0, 0); \
    x3 = __builtin_amdgcn_mfma_f32_16x16x32_bf16(AX, b3_, x3, 0, 0, 0); \
    y3 = __builtin_amdgcn_mfma_f32_16x16x32_bf16(AY, b3_, y3, 0, 0, 0); }

// general merge (boundary tiles): per-element depth mask, desc from LDS
#define RMG(K1, K2, EL, DV) { \
    unsigned pb_ = (__builtin_bit_cast(unsigned, EL) & 0xFFFFC000u) | e_; \
    float sf_ = __builtin_bit_cast(float, (du_ < (DV)) ? pb_ : negp_); \
    K2 = __builtin_amdgcn_fmed3f(K1, K2, sf_); \
    K1 = fmaxf(K1, sf_); }

#define MGEN(nb, XA, YA) { \
    unsigned pk_ = eds[ebase + (nb) * 16 + lane16]; \
    int du_ = (int)(pk_ >> 16); \
    unsigned e_ = pk_ & 0x3FFFu; \
    unsigned negp_ = negbase | e_; \
    RMG(k1x0, k2x0, XA[0], dvx0) RMG(k1x1, k2x1, XA[1], dvx1) \
    RMG(k1x2, k2x2, XA[2], dvx2) RMG(k1x3, k2x3, XA[3], dvx3) \
    RMG(k1y0, k2y0, YA[0], dvy0) RMG(k1y1, k2y1, YA[1], dvy1) \
    RMG(k1y2, k2y2, YA[2], dvy2) RMG(k1y3, k2y3, YA[3], dvy3) }

// fast merge (tile fully valid for all 32 rows of the wave): no mask
#define RMF(K1, K2, EL) { \
    float sf_ = __builtin_bit_cast(float, \
        (__builtin_bit_cast(unsigned, EL) & 0xFFFFC000u) | e_); \
    K2 = __builtin_amdgcn_fmed3f(K1, K2, sf_); \
    K1 = fmaxf(K1, sf_); }

#define MFAST(nb, XA, YA) { \
    unsigned e_ = eds[ebase + (nb) * 16 + lane16] & 0x3FFFu; \
    RMF(k1x0, k2x0, XA[0]) RMF(k1x1, k2x1, XA[1]) \
    RMF(k1x2, k2x2, XA[2]) RMF(k1x3, k2x3, XA[3]) \
    RMF(k1y0, k2y0, YA[0]) RMF(k1y1, k2y1, YA[1]) \
    RMF(k1y2, k2y2, YA[2]) RMF(k1y3, k2y3, YA[3]) }

#define BF1(K1, K2, m) { \
    float o1_ = __shfl_xor(K1, m, 64); \
    float o2_ = __shfl_xor(K2, m, 64); \
    float m2_ = fmaxf(K2, o2_); \
    K2 = __builtin_amdgcn_fmed3f(K1, o1_, m2_); \
    K1 = fmaxf(K1, o1_); }

#define BFALL(m) \
    BF1(k1x0, k2x0, m) BF1(k1x1, k2x1, m) BF1(k1x2, k2x2, m) BF1(k1x3, k2x3, m) \
    BF1(k1y0, k2y0, m) BF1(k1y1, k2y1, m) BF1(k1y2, k2y2, m) BF1(k1y3, k2y3, m)

#define EMIT2(K1, K2, GROW) { \
    size_t o = ((size_t)seg * NN + (GROW)) * 2; \
    pv[o] = K1; pv[o + 1] = K2; }

__global__ __launch_bounds__(256) void k_score_top2_mfma(
        const __hip_bfloat16* __restrict__ htb,
        const __hip_bfloat16* __restrict__ hsb,
        const int* __restrict__ sdep, const int* __restrict__ sidx,
        const int* __restrict__ bofs,
        float* __restrict__ pv) {
    __shared__ float4 Bs4[2][64 * 16];   // 32 KB double buffer (B only)
    __shared__ unsigned eds[12 * 64];    // 3 KB packed (depth<<16)|(0x3FFF-sidx)
    int tid = threadIdx.x;
    int w = tid >> 6;
    int l = tid & 63;
    int lane16 = l & 15;
    int quad = l >> 4;
    int rb = (int)gridDim.x - 1 - (int)blockIdx.x;  // heavy blocks first
    int row0 = rb * 128;
    int seg = blockIdx.y;
    const unsigned negbase = __builtin_bit_cast(unsigned, NEGV) & 0xFFFFC000u;

    // balanced split: ns = ceil(nt/12) active segments (<= 16), ~12 tiles ea.
    int dmax = sdep[row0 + 127];
    int lim = bofs[dmax];
    int nt = (lim + 63) >> 6;               // total tiles, <= 192
    int ns = (nt + 11) / 12;
    if (ns < 1) ns = 1;
    if (seg >= ns) {
        if (tid < 128) {
            int grow = sidx[row0 + tid];
            size_t o = ((size_t)seg * NN + grow) * 2;
            pv[o]     = __builtin_bit_cast(float, negbase | 0x3FFFu);
            pv[o + 1] = __builtin_bit_cast(float, negbase | 0x3FFEu);
        }
        return;
    }
    int t0 = (seg * nt) / ns;
    int t1 = ((seg + 1) * nt) / ns;

    // A fragments: 32 sorted target rows per wave, two 16-row MFMA groups.
    int rbase = row0 + w * 32;
    s8v ax0, ax1, ax2, ax3, ay0, ay1, ay2, ay3;
    {
        const float4* gx = (const float4*)(htb + (size_t)(rbase + lane16) * HD);
        ax0 = __builtin_bit_cast(s8v, gx[quad]);
        ax1 = __builtin_bit_cast(s8v, gx[4 + quad]);
        ax2 = __builtin_bit_cast(s8v, gx[8 + quad]);
        ax3 = __builtin_bit_cast(s8v, gx[12 + quad]);
        const float4* gy = (const float4*)(htb + (size_t)(rbase + 16 + lane16) * HD);
        ay0 = __builtin_bit_cast(s8v, gy[quad]);
        ay1 = __builtin_bit_cast(s8v, gy[4 + quad]);
        ay2 = __builtin_bit_cast(s8v, gy[8 + quad]);
        ay3 = __builtin_bit_cast(s8v, gy[12 + quad]);
    }
    // pack candidate descriptors for the whole segment into LDS (once);
    // consumed only after the first loop-top barrier.
    for (int i = tid; i < (t1 - t0) * 64; i += 256) {
        int p = t0 * 64 + i;
        eds[i] = ((unsigned)sdep[p] << 16) | (0x3FFFu - (unsigned)sidx[p]);
    }
    if (t0 < t1) {   // stage first tile into the parity-matching buffer
        float4* B0 = Bs4[t0 & 1];
        const float4* gb = (const float4*)(hsb + (size_t)(t0 * 64) * HD);
        float4 b0_ = gb[tid], b1_ = gb[tid + 256], b2_ = gb[tid + 512], b3_ = gb[tid + 768];
        STG(B0, tid, b0_) STG(B0, tid + 256, b1_)
        STG(B0, tid + 512, b2_) STG(B0, tid + 768, b3_)
    }

    int bbase = lane16 * 16, brm = lane16 & 7;

    int dvx0 = sdep[rbase + quad * 4 + 0];
    int dvx1 = sdep[rbase + quad * 4 + 1];
    int dvx2 = sdep[rbase + quad * 4 + 2];
    int dvx3 = sdep[rbase + quad * 4 + 3];
    int dvy0 = sdep[rbase + 16 + quad * 4 + 0];
    int dvy1 = sdep[rbase + 16 + quad * 4 + 1];
    int dvy2 = sdep[rbase + 16 + quad * 4 + 2];
    int dvy3 = sdep[rbase + 16 + quad * 4 + 3];
    // wave window: cands < lim_lo valid for EVERY row; >= lim_hi for none.
    int lim_lo = bofs[sdep[rbase]];
    int lim_hi = bofs[sdep[rbase + 31]];

    // defaults: packed NEGV for orig u=0 (k1) and u=1 (k2), lane16==0 only.
    float ki1 = (lane16 == 0) ? __builtin_bit_cast(float, negbase | 0x3FFFu) : -3.4e38f;
    float ki2 = (lane16 == 0) ? __builtin_bit_cast(float, negbase | 0x3FFEu) : -3.4e38f;
    float k1x0 = ki1, k1x1 = ki1, k1x2 = ki1, k1x3 = ki1;
    float k1y0 = ki1, k1y1 = ki1, k1y2 = ki1, k1y3 = ki1;
    float k2x0 = ki2, k2x1 = ki2, k2x2 = ki2, k2x3 = ki2;
    float k2y0 = ki2, k2y1 = ki2, k2y2 = ki2, k2y3 = ki2;

    float4 p0, p1, p2, p3;
    for (int t = t0; t < t1; ++t) {
        int u0 = t * 64;
        int ebase = (t - t0) * 64;
        __syncthreads();
        if (t + 1 < t1) {
            const float4* g = (const float4*)(hsb + (size_t)(u0 + 64) * HD);
            p0 = g[tid]; p1 = g[tid + 256]; p2 = g[tid + 512]; p3 = g[tid + 768];
        }
        if (u0 < lim_hi) {          // wave-uniform: tile matters for >=1 row
            const float4* B = Bs4[t & 1];
            f4v x0 = (f4v){0.f, 0.f, 0.f, 0.f};
            f4v x1 = (f4v){0.f, 0.f, 0.f, 0.f};
            f4v x2 = (f4v){0.f, 0.f, 0.f, 0.f};
            f4v x3 = (f4v){0.f, 0.f, 0.f, 0.f};
            f4v y0 = (f4v){0.f, 0.f, 0.f, 0.f};
            f4v y1 = (f4v){0.f, 0.f, 0.f, 0.f};
            f4v y2 = (f4v){0.f, 0.f, 0.f, 0.f};
            f4v y3 = (f4v){0.f, 0.f, 0.f, 0.f};
            KC2(0, ax0, ay0) KC2(1, ax1, ay1) KC2(2, ax2, ay2) KC2(3, ax3, ay3)
            if (u0 + 64 <= lim_lo) {   // fully valid for all 32 rows
                MFAST(0, x0, y0) MFAST(1, x1, y1)
                MFAST(2, x2, y2) MFAST(3, x3, y3)
            } else {                   // boundary: per-element depth mask
                MGEN(0, x0, y0) MGEN(1, x1, y1)
                MGEN(2, x2, y2) MGEN(3, x3, y3)
            }
        }
        if (t + 1 < t1) {
            float4* Bn = Bs4[(t + 1) & 1];
            STG(Bn, tid, p0) STG(Bn, tid + 256, p1)
            STG(Bn, tid + 512, p2) STG(Bn, tid + 768, p3)
        }
    }

    BFALL(1) BFALL(2) BFALL(4) BFALL(8)

    if (lane16 == 0) {
        int gbse = rbase + quad * 4;
        EMIT2(k1x0, k2x0, sidx[gbse + 0])
        EMIT2(k1x1, k2x1, sidx[gbse + 1])
        EMIT2(k1x2, k2x2, sidx[gbse + 2])
        EMIT2(k1x3, k2x3, sidx[gbse + 3])
        EMIT2(k1y0, k2y0, sidx[gbse + 16])
        EMIT2(k1y1, k2y1, sidx[gbse + 17])
        EMIT2(k1y2, k2y2, sidx[gbse + 18])
        EMIT2(k1y3, k2y3, sidx[gbse + 19])
    }
}

// ONE kernel writes ALL outputs (f32): parallel packed merge (r15-proven).
__global__ __launch_bounds__(256) void k_final(const float* __restrict__ pv,
                                               const int* __restrict__ ntype,
                                               const int* __restrict__ ndepth,
                                               const float* __restrict__ A,
                                               const float* __restrict__ B,
                                               const float* __restrict__ Wi2,
                                               const float* __restrict__ bi2,
                                               float* __restrict__ out) {
    int tid = threadIdx.x;
    int lane = tid & 63;
    int v = blockIdx.x * 4 + (tid >> 6);

    float k1 = -3.4e38f;
    if (lane < 32) {
        k1 = pv[((size_t)(lane >> 1) * NN + v) * 2 + (lane & 1)];
    }
    float k2 = -3.4e38f;
#pragma unroll
    for (int m = 1; m <= 16; m <<= 1) {
        float o1 = __shfl_xor(k1, m, 64);
        float o2 = __shfl_xor(k2, m, 64);
        float m2 = fmaxf(k2, o2);
        k2 = __builtin_amdgcn_fmed3f(k1, o1, m2);
        k1 = fmaxf(k1, o1);
    }
    float K1 = __shfl(k1, 0, 64);
    float K2 = __shfl(k2, 0, 64);
    unsigned b1 = __builtin_bit_cast(unsigned, K1);
    unsigned b2 = __builtin_bit_cast(unsigned, K2);
    int I1 = 0x3FFF - (int)(b1 & 0x3FFFu);
    int I2 = 0x3FFF - (int)(b2 & 0x3FFFu);

    if (lane == 0) {
        int tp = ntype[v];
        bool tv = (tp != 0) && (ndepth[v] > 0) && (K1 > -5.0e8f);  // NEG/2
        out[2 * NN + 2 * v]     = K1;
        out[2 * NN + 2 * v + 1] = K2;
        out[4 * NN + 2 * v]     = (float)I1;
        out[4 * NN + 2 * v + 1] = (float)I2;
        out[6 * NN + 2 * v]     = tv ? 1.f : 0.f;
        out[6 * NN + 2 * v + 1] = (tv && tp == 2) ? 1.f : 0.f;
    }

    int u1 = min(max(I1, 0), NN - 1);
    int u2 = min(max(I2, 0), NN - 1);
    const float2* A2p = (const float2*)A;
    float2 av1 = A2p[(size_t)u1 * 64 + lane];
    float2 av2 = A2p[(size_t)u2 * 64 + lane];
    float2 bv = ((const float2*)B)[(size_t)v * 64 + lane];
    float2 wv = ((const float2*)Wi2)[lane];
    float bias = bi2[0];
    float a1 = fmaf(fmaxf(av1.x + bv.x, 0.f), wv.x,
                    fmaxf(av1.y + bv.y, 0.f) * wv.y);
    float a2 = fmaf(fmaxf(av2.x + bv.x, 0.f), wv.x,
                    fmaxf(av2.y + bv.y, 0.f) * wv.y);
#pragma unroll
    for (int off = 32; off > 0; off >>= 1) {
        a1 += __shfl_down(a1, off);
        a2 += __shfl_down(a2, off);
    }
    if (lane == 0) {
        out[2 * v]     = 1.f / (1.f + expf(-(a1 + bias)));
        out[2 * v + 1] = 1.f / (1.f + expf(-(a2 + bias)));
    }
}

extern "C" void kernel_launch(void* const* d_in, const int* in_sizes, int n_in,
                              void* d_out, int out_size, void* d_ws, size_t ws_size,
                              hipStream_t stream) {
    (void)in_sizes; (void)n_in; (void)out_size; (void)ws_size;
    const float* x   = (const float*)d_in[0];
    const float* z   = (const float*)d_in[1];
    const int* ntype = (const int*)d_in[2];
    const int* ndep  = (const int*)d_in[3];
    const int* eidx  = (const int*)d_in[4];
    const float* W1  = (const float*)d_in[5];
    const float* b1  = (const float*)d_in[6];
    const float* W2  = (const float*)d_in[7];
    const float* b2  = (const float*)d_in[8];
    const float* Wm1 = (const float*)d_in[9];
    const float* bm1 = (const float*)d_in[10];
    const float* Wm2 = (const float*)d_in[11];
    const float* bm2 = (const float*)d_in[12];
    const float* Wsm = (const float*)d_in[13];
    const float* Wtm = (const float*)d_in[14];
    const float* Wi1 = (const float*)d_in[15];
    const float* bi1 = (const float*)d_in[16];
    const float* Wi2 = (const float*)d_in[17];
    const float* bi2 = (const float*)d_in[18];
    float* out = (float*)d_out;

    const int* esrc = eidx;
    const int* edst = eidx + NE;

    // Workspace layout (~24.5 MiB). The pi spacer hosts line-padded cnt/dcur;
    // the old ebw slot ([NE] floats) now hosts xi[NN] float4 (16B-aligned).
    const size_t S2N = (size_t)SEG * 2 * NN;  // 393216
    float* ws = (float*)d_ws;
    float* pv     = ws;                       // [S2N] f (packed scores)
    int*   pi     = (int*)(pv + S2N);         // [S2N] i (spacer)
    int*   cnt    = pi;                       // [64*16] padded depth counts
    int*   dcur   = pi + 1024;                // [64*16] padded depth cursors
    int*   degi   = pi + S2N;                 // [NN]   (memset)
    float* inv    = (float*)(degi + NN + 64); // [NN]  (old cnt slot = pad)
    float* agg2   = inv + NN;                 // [2NN]
    float* cz1    = agg2 + 2 * NN;            // [128]
    float* cz2    = cz1 + 128;                // [128]
    int*   offs   = (int*)(cz2 + 128);        // [NN+16]
    int*   cursor = offs + NN + 16;           // [NN]
    int*   bofs   = cursor + NN;              // [80]
    int*   sidx   = bofs + 80 + 64;           // [NN] (old dcur slot = pad)
    int*   sdep   = sidx + NN;                // [NN]
    int*   prank  = sdep + NN;                // [NN]
    int*   ebsrc  = prank + NN;               // [NE]
    float* ebwslot= (float*)(ebsrc + NE);     // [NE] (xi lives here)
    float4* xi    = (float4*)ebwslot;         // [NN] packed (x0,x1,inv,0)
    __hip_bfloat16* wt7 = (__hip_bfloat16*)(ebwslot + NE);  // [7*16384] bf16
    size_t F = (size_t)NN * HD;
    float* s0 = (float*)(wt7 + 7 * 16384);    // h1c (bf16) -> {htb_s, hsb_s}
    float* s1 = s0 + F;                       // aggH -> B (in-place)
    float* s2 = s1 + F;                       // A
    unsigned short* h1b = (unsigned short*)s0;
    __hip_bfloat16* htb = (__hip_bfloat16*)s0;
    __hip_bfloat16* hsb = htb + F;

    hipMemsetAsync(degi, 0, NN * sizeof(int), stream);
    hipMemsetAsync(cnt, 0, 1024 * sizeof(int), stream);
    k_counts_wz<<<NE / 256 + NN / 256 + 56 + 1, 256, 0, stream>>>(
        edst, ndep, W2, Wm1, Wm2, Wtm, Wsm, Wi1, z, bm1, bi1,
        degi, cnt, wt7, cz1, cz2);
    k_prefix<<<1, 1024, 0, stream>>>(degi, cnt, x, inv, agg2, xi, offs, cursor,
                                     bofs, dcur);
    k_bucket_scatter<<<NE / 256 + NN / 256, 256, 0, stream>>>(
        esrc, edst, ndep, cursor, ebsrc, dcur, sidx, sdep, prank);
    k_gl1<<<NN / 32, 256, 0, stream>>>(offs, ebsrc, xi, agg2, W1, b1, inv,
                                       h1b, s1);
    k_gatherH<<<NN / 4, 256, 0, stream>>>(offs, ebsrc, inv, h1b, s1);
    k_mlp7_mfma<<<NN / 16, 256, 0, stream>>>(s1, wt7, b2, cz1, bm2, cz2,
                                             prank, s2, s1, htb, hsb);
    k_score_top2_mfma<<<dim3(NN / 128, SEG), 256, 0, stream>>>(
        htb, hsb, sdep, sidx, bofs, pv);
    k_final<<<NN / 4, 256, 0, stream>>>(pv, ntype, ndep, s2, s1, Wi2, bi2, out);
}

// Round 10
// 220.547 us; speedup vs baseline: 1.0643x; 1.0194x over previous
//
#include <hip/hip_runtime.h>
#include <hip/hip_bf16.h>

#define NN 12288
#define NE 196608
#define HD 128
#define ZD 128
#define NEGV (-1.0e9f)
#define SEG 16

using s8v = __attribute__((ext_vector_type(8))) short;  // 8 bf16 = 4 VGPRs
using f4v = __attribute__((ext_vector_type(4))) float;  // 4 fp32 acc
using i4v = __attribute__((ext_vector_type(4))) int;

__device__ __forceinline__ unsigned short f2bf(float f) {
    return __builtin_bit_cast(unsigned short, __float2bfloat16(f));
}
__device__ __forceinline__ float4 pack8(float4 a, float4 b) {
    unsigned p0 = ((unsigned)f2bf(a.y) << 16) | f2bf(a.x);
    unsigned p1 = ((unsigned)f2bf(a.w) << 16) | f2bf(a.z);
    unsigned p2 = ((unsigned)f2bf(b.y) << 16) | f2bf(b.x);
    unsigned p3 = ((unsigned)f2bf(b.w) << 16) | f2bf(b.z);
    i4v r = (i4v){(int)p0, (int)p1, (int)p2, (int)p3};
    return __builtin_bit_cast(float4, r);
}

// Mega split-grid of INDEPENDENT prep work:
// [0,768): edge in-degree count; [768,816): depth-bucket count (LDS hist ->
// line-padded counters); [816,872): 7x weight transpose via LDS tiles;
// [872]: cz1/cz2.
__global__ __launch_bounds__(256) void k_counts_wz(
        const int* __restrict__ edst, const int* __restrict__ ndep,
        const float* __restrict__ W2, const float* __restrict__ Wm1,
        const float* __restrict__ Wm2, const float* __restrict__ Wtm,
        const float* __restrict__ Wsm, const float* __restrict__ Wi1,
        const float* __restrict__ z, const float* __restrict__ bm1,
        const float* __restrict__ bi1,
        int* degi, int* cnt, __hip_bfloat16* __restrict__ wt7,
        float* cz1, float* cz2) {
    __shared__ int lh[64];
    __shared__ float tl[16 * 129];   // padded transpose tile (8.25 KB)
    int tid = threadIdx.x;
    int bid = blockIdx.x;
    if (bid < NE / 256) {
        int e = bid * 256 + tid;
        atomicAdd(&degi[edst[e]], 1);
    } else if (bid < NE / 256 + NN / 256) {
        // depth histogram: LDS-aggregate, then 1 global atomic per depth per
        // block onto stride-16 (one-per-cacheline) counters.
        if (tid < 64) lh[tid] = 0;
        __syncthreads();
        int v = (bid - NE / 256) * 256 + tid;
        atomicAdd(&lh[ndep[v]], 1);
        __syncthreads();
        if (tid < 64) {
            int c = lh[tid];
            if (c) atomicAdd(&cnt[tid * 16], c);
        }
    } else if (bid < NE / 256 + NN / 256 + 56) {
        // weight transpose: one block = one 16(k)x128(n) slice of one matrix.
        int b2 = bid - NE / 256 - NN / 256;   // 0..55
        int g = b2 >> 3;
        int k0 = (b2 & 7) << 4;
        const float* src;
        if (g == 0) src = W2;
        else if (g == 1) src = Wm1;
        else if (g == 2) src = Wm2;
        else if (g == 3) src = Wtm;
        else if (g == 4) src = Wsm;
        else if (g == 5) src = Wi1;
        else src = Wi1 + 128 * HD;
#pragma unroll
        for (int i = 0; i < 8; ++i) {         // coalesced f32 reads
            int idx = i * 256 + tid;
            int kk = idx >> 7, n = idx & 127;
            tl[kk * 129 + n] = src[(k0 + kk) * 128 + n];
        }
        __syncthreads();
#pragma unroll
        for (int i = 0; i < 8; ++i) {         // 32B-run bf16 writes
            int idx = i * 256 + tid;
            int n = idx >> 4, kk = idx & 15;
            wt7[(g << 14) + n * 128 + k0 + kk] = __float2bfloat16(tl[kk * 129 + n]);
        }
    } else {
        int j = tid & 127;
        const float* W = (tid < 128) ? (Wm1 + HD * HD) : (Wi1 + 2 * HD * HD);
        float A0 = 0.f, A1 = 0.f, A2 = 0.f, A3 = 0.f;
        for (int k = 0; k < ZD; k += 4) {
            A0 = fmaf(z[k],     W[(k    ) * HD + j], A0);
            A1 = fmaf(z[k + 1], W[(k + 1) * HD + j], A1);
            A2 = fmaf(z[k + 2], W[(k + 2) * HD + j], A2);
            A3 = fmaf(z[k + 3], W[(k + 3) * HD + j], A3);
        }
        float r = (A0 + A1) + (A2 + A3);
        if (tid < 128) cz1[j] = r + bm1[j];
        else           cz2[j] = r + bi1[j];
    }
}

// ONE block, 1024 threads: CSR offsets (+cursor), inv = rsqrt(deg+1), agg2
// self term, xi = (x.x, x.y, inv, 0) packed float4, plus (tid 0) the
// 64-bucket depth scan -> bofs/dcur.
__global__ __launch_bounds__(1024) void k_prefix(const int* __restrict__ degi,
                                                 const int* __restrict__ cnt,
                                                 const float* __restrict__ x,
                                                 float* inv, float* agg2,
                                                 float4* __restrict__ xi,
                                                 int* offs, int* cursor,
                                                 int* bofs, int* dcur) {
    __shared__ int ldeg[NN];     // 48 KB: degi, then overwritten by prefix
    __shared__ int part[1024];   // 4 KB
    __shared__ int stot;
    int tid = threadIdx.x;
#pragma unroll
    for (int k = 0; k < 12; ++k)          // coalesced: lane-stride 4B
        ldeg[k * 1024 + tid] = degi[k * 1024 + tid];
    __syncthreads();
    int base = tid * 12;
    int s = 0;
#pragma unroll
    for (int k = 0; k < 12; ++k) s += ldeg[base + k];
    part[tid] = s;
    __syncthreads();
    for (int off = 1; off < 1024; off <<= 1) {
        int v = (tid >= off) ? part[tid - off] : 0;
        __syncthreads();
        part[tid] += v;
        __syncthreads();
    }
    int run = part[tid] - s;  // exclusive base for this thread's 12 elems
#pragma unroll
    for (int k = 0; k < 12; ++k) {        // overwrite LDS with excl prefix
        int d = ldeg[base + k];
        ldeg[base + k] = run;
        run += d;
    }
    if (tid == 1023) stot = run;          // grand total
    __syncthreads();
    int total = stot;
    const float2* X2 = (const float2*)x;
    float2* A2 = (float2*)agg2;
#pragma unroll
    for (int k = 0; k < 12; ++k) {        // coalesced output phase
        int i = k * 1024 + tid;
        int p = ldeg[i];
        int nxt = (i < NN - 1) ? ldeg[i + 1] : total;
        int d = nxt - p;                  // recover degree
        offs[i] = p;
        cursor[i] = p;
        float iv = rsqrtf((float)(d + 1));
        inv[i] = iv;
        float w = iv * iv;
        float2 xv = X2[i];
        float2 av; av.x = xv.x * w; av.y = xv.y * w;
        A2[i] = av;
        float4 xo; xo.x = xv.x; xo.y = xv.y; xo.z = iv; xo.w = 0.f;
        xi[i] = xo;
    }
    if (tid == 0) {
        offs[NN] = total;
        int r = 0;                        // depth-bucket exclusive scan
        for (int d = 0; d < 64; ++d) {
            bofs[d] = r;
            dcur[d * 16] = r;
            r += cnt[d * 16];
        }
        bofs[64] = r;
    }
}

// Split grid: blocks [0,768) bucket edges (ebsrc only — separable norm);
// [768,816) depth-sort scatter (LDS local-rank + padded atomics).
__global__ __launch_bounds__(256) void k_bucket_scatter(
        const int* __restrict__ esrc, const int* __restrict__ edst,
        const int* __restrict__ ndep,
        int* cursor, int* ebsrc,
        int* dcur, int* sidx, int* sdep, int* prank) {
    __shared__ int lh[64];
    __shared__ int lbase[64];
    int tid = threadIdx.x;
    if (blockIdx.x < NE / 256) {
        int e = blockIdx.x * 256 + tid;
        int u = esrc[e], v = edst[e];
        int pos = atomicAdd(&cursor[v], 1);
        ebsrc[pos] = u;
    } else {
        if (tid < 64) lh[tid] = 0;
        __syncthreads();
        int v = (blockIdx.x - NE / 256) * 256 + tid;
        int d = ndep[v];
        int r = atomicAdd(&lh[d], 1);          // local rank within block
        __syncthreads();
        if (tid < 64) {
            int c = lh[tid];
            if (c) lbase[tid] = atomicAdd(&dcur[tid * 16], c);
        }
        __syncthreads();
        int p = lbase[d] + r;
        sidx[p] = v;
        sdep[p] = d;
        prank[v] = p;
    }
}

// FUSED layer-1 gather + lin1. Phase 1: 8 lanes/node accumulate
// inv[u]*x[u] from ONE aligned 16B xi load per edge; scale by inv[v] once.
// Phase 2: h1c = relu(agg @ W1 + b1) * inv[v] (bf16, pre-scaled) and aggH
// self-loop seed.
__global__ __launch_bounds__(256) void k_gl1(const int* __restrict__ offs,
                                             const int* __restrict__ ebsrc,
                                             const float4* __restrict__ xi,
                                             const float* __restrict__ agg2,
                                             const float* __restrict__ W1,
                                             const float* __restrict__ b1,
                                             const float* __restrict__ inv,
                                             unsigned short* h1b, float* aggH) {
    __shared__ float2 la[32];
    int tid = threadIdx.x;
    int v0 = blockIdx.x * 32;
    {   // phase 1: edge gather, 8 lanes/node
        int nb = tid >> 3;
        int sl = tid & 7;
        int v = v0 + nb;
        int b = offs[v], e = offs[v + 1];
        float ax = 0.f, ay = 0.f;
        for (int k = b + sl; k < e; k += 8) {
            int u = ebsrc[k];
            float4 xv = xi[u];                 // (x0, x1, inv_u, 0)
            ax = fmaf(xv.x, xv.z, ax);
            ay = fmaf(xv.y, xv.z, ay);
        }
#pragma unroll
        for (int m = 1; m < 8; m <<= 1) {   // 8-lane groups are lane-aligned
            ax += __shfl_xor(ax, m, 64);
            ay += __shfl_xor(ay, m, 64);
        }
        if (sl == 0) {
            float ivv = inv[v];
            float2 seed = ((const float2*)agg2)[v];  // self term (k_prefix)
            seed.x = fmaf(ax, ivv, seed.x);
            seed.y = fmaf(ay, ivv, seed.y);
            la[nb] = seed;
        }
    }
    __syncthreads();
    {   // phase 2: 32 nodes x 128 cols = 4096 outputs, 16 per thread
#pragma unroll
        for (int k = 0; k < 16; ++k) {
            int idx = k * 256 + tid;
            int vloc = idx >> 7, j = idx & 127;
            float2 a = la[vloc];
            float hv = fmaxf(fmaf(a.x, W1[j], fmaf(a.y, W1[HD + j], b1[j])), 0.f);
            int t = (v0 + vloc) * HD + j;
            float iv = inv[v0 + vloc];
            h1b[t] = f2bf(hv * iv);            // pre-scaled h1c
            aggH[t] = hv * iv * iv;            // self-loop seed (exact f32)
        }
    }
}

// ===== FUSED layer-2 aggregation + 7-GEMM MLP chain =====
// v18: each block's 4 waves first compute the layer-2 aggregation for the
// block's 16 rows (4 nodes/wave; identical arithmetic to the old k_gatherH:
// sum pre-scaled h1c rows, one fmaf by inv[v], seed from k_gl1's aggH) into
// 8 KB LDS, then run the GEMM chain from LDS. Removes one dispatch and the
// aggH global write+re-read round-trip.
#define AFRAGS(BUF) \
    s8v a0_ = __builtin_bit_cast(s8v, (BUF)[lane16 * 16 + ((quad     ) ^ lane16)]); \
    s8v a1_ = __builtin_bit_cast(s8v, (BUF)[lane16 * 16 + ((quad +  4) ^ lane16)]); \
    s8v a2_ = __builtin_bit_cast(s8v, (BUF)[lane16 * 16 + ((quad +  8) ^ lane16)]); \
    s8v a3_ = __builtin_bit_cast(s8v, (BUF)[lane16 * 16 + ((quad + 12) ^ lane16)]);

#define NBACC(WT4, NCOL, ACC) \
    f4v ACC = (f4v){0.f, 0.f, 0.f, 0.f}; \
    ACC = __builtin_amdgcn_mfma_f32_16x16x32_bf16(a0_, __builtin_bit_cast(s8v, (WT4)[(NCOL) * 16 + quad     ]), ACC, 0, 0, 0); \
    ACC = __builtin_amdgcn_mfma_f32_16x16x32_bf16(a1_, __builtin_bit_cast(s8v, (WT4)[(NCOL) * 16 + quad +  4]), ACC, 0, 0, 0); \
    ACC = __builtin_amdgcn_mfma_f32_16x16x32_bf16(a2_, __builtin_bit_cast(s8v, (WT4)[(NCOL) * 16 + quad +  8]), ACC, 0, 0, 0); \
    ACC = __builtin_amdgcn_mfma_f32_16x16x32_bf16(a3_, __builtin_bit_cast(s8v, (WT4)[(NCOL) * 16 + quad + 12]), ACC, 0, 0, 0);

#define BST(EXPR, RR, COL, USPTR) { int rw_ = quad * 4 + (RR); int cc_ = (COL) >> 3; \
    (USPTR)[rw_ * 128 + (((cc_ ^ rw_)) << 3) + ((COL) & 7)] = f2bf(EXPR); }

#define LDS4R(ACC, B, COL, US) \
    BST(fmaxf(ACC[0] + (B), 0.f), 0, COL, US) BST(fmaxf(ACC[1] + (B), 0.f), 1, COL, US) \
    BST(fmaxf(ACC[2] + (B), 0.f), 2, COL, US) BST(fmaxf(ACC[3] + (B), 0.f), 3, COL, US)

#define LDS4(ACC, B, COL, US) \
    BST(ACC[0] + (B), 0, COL, US) BST(ACC[1] + (B), 1, COL, US) \
    BST(ACC[2] + (B), 2, COL, US) BST(ACC[3] + (B), 3, COL, US)

#define GBF4S(ACC, COL, PTR) \
    ((unsigned short*)(PTR))[(size_t)pr0 * HD + (COL)] = f2bf(ACC[0]); \
    ((unsigned short*)(PTR))[(size_t)pr1 * HD + (COL)] = f2bf(ACC[1]); \
    ((unsigned short*)(PTR))[(size_t)pr2 * HD + (COL)] = f2bf(ACC[2]); \
    ((unsigned short*)(PTR))[(size_t)pr3 * HD + (COL)] = f2bf(ACC[3]);

#define GF4(ACC, B, COL, PTR) \
    (PTR)[(size_t)(r0 + quad * 4 + 0) * HD + (COL)] = ACC[0] + (B); \
    (PTR)[(size_t)(r0 + quad * 4 + 1) * HD + (COL)] = ACC[1] + (B); \
    (PTR)[(size_t)(r0 + quad * 4 + 2) * HD + (COL)] = ACC[2] + (B); \
    (PTR)[(size_t)(r0 + quad * 4 + 3) * HD + (COL)] = ACC[3] + (B);

__global__ __launch_bounds__(256) void k_ghmlp7(
        const int* __restrict__ offs, const int* __restrict__ ebsrc,
        const float* __restrict__ inv, const unsigned short* __restrict__ h1b,
        const float* __restrict__ s1in, const __hip_bfloat16* __restrict__ wt7,
        const float* __restrict__ bb2, const float* __restrict__ bcz1,
        const float* __restrict__ bbm2, const float* __restrict__ bcz2,
        const int* __restrict__ prank,
        float* __restrict__ outA, float* __restrict__ outB,
        __hip_bfloat16* __restrict__ htb, __hip_bfloat16* __restrict__ hsb) {
    __shared__ float4 bufA4[256];   // 4 KB
    __shared__ float4 bufB4[256];   // 4 KB
    __shared__ float laggH[16 * 128];  // 8 KB: this block's agg rows (f32)
    int tid = threadIdx.x;
    int wv = tid >> 6;
    int l = tid & 63;
    int lane16 = l & 15;
    int quad = l >> 4;
    int r0 = blockIdx.x * 16;
    const float4* wt4 = (const float4*)wt7;

    int pr0 = prank[r0 + quad * 4 + 0];
    int pr1 = prank[r0 + quad * 4 + 1];
    int pr2 = prank[r0 + quad * 4 + 2];
    int pr3 = prank[r0 + quad * 4 + 3];

    {   // fused layer-2 aggregation: 4 nodes per wave, lane = column pair
        const unsigned* H1 = (const unsigned*)h1b;
        const float2* S2r = (const float2*)s1in;   // seeds from k_gl1
        float2* LG2 = (float2*)laggH;
#pragma unroll
        for (int j = 0; j < 4; ++j) {
            int v = r0 + wv * 4 + j;
            float2 acc; acc.x = 0.f; acc.y = 0.f;
            int b = offs[v], e = offs[v + 1];
            int k = b;
            for (; k + 4 <= e; k += 4) {
                int u0 = ebsrc[k], u1 = ebsrc[k + 1];
                int u2 = ebsrc[k + 2], u3 = ebsrc[k + 3];
                unsigned hb0 = H1[(size_t)u0 * 64 + l];
                unsigned hb1 = H1[(size_t)u1 * 64 + l];
                unsigned hb2 = H1[(size_t)u2 * 64 + l];
                unsigned hb3 = H1[(size_t)u3 * 64 + l];
                acc.x += __builtin_bit_cast(float, hb0 << 16);
                acc.y += __builtin_bit_cast(float, hb0 & 0xFFFF0000u);
                acc.x += __builtin_bit_cast(float, hb1 << 16);
                acc.y += __builtin_bit_cast(float, hb1 & 0xFFFF0000u);
                acc.x += __builtin_bit_cast(float, hb2 << 16);
                acc.y += __builtin_bit_cast(float, hb2 & 0xFFFF0000u);
                acc.x += __builtin_bit_cast(float, hb3 << 16);
                acc.y += __builtin_bit_cast(float, hb3 & 0xFFFF0000u);
            }
            for (; k < e; ++k) {
                int u = ebsrc[k];
                unsigned hb = H1[(size_t)u * 64 + l];
                acc.x += __builtin_bit_cast(float, hb << 16);
                acc.y += __builtin_bit_cast(float, hb & 0xFFFF0000u);
            }
            float ivv = inv[v];
            float2 seed = S2r[(size_t)v * 64 + l];
            seed.x = fmaf(acc.x, ivv, seed.x);
            seed.y = fmaf(acc.y, ivv, seed.y);
            LG2[(wv * 4 + j) * 64 + l] = seed;
        }
    }
    __syncthreads();
    {   // pack agg rows (LDS f32) -> bufA (bf16, swizzled)
        const float4* g4 = (const float4*)laggH;
        float4 u0 = g4[2 * tid], u1 = g4[2 * tid + 1];
        int row_ = tid >> 4, c_ = tid & 15;
        bufA4[row_ * 16 + (c_ ^ row_)] = pack8(u0, u1);
    }
    __syncthreads();
    int col0 = wv * 32 + lane16, col1 = col0 + 16;
    unsigned short* usA = (unsigned short*)bufA4;
    unsigned short* usB = (unsigned short*)bufB4;

    {   // G1: h2 = relu(aggH @ W2 + b2) -> bufB
        AFRAGS(bufA4)
        NBACC(wt4, col0, cA) NBACC(wt4, col1, cB)
        float q0 = bb2[col0], q1 = bb2[col1];
        LDS4R(cA, q0, col0, usB) LDS4R(cB, q1, col1, usB)
    }
    __syncthreads();
    {   // G2: t = relu(h2 @ Wm1 + cz1) -> bufA
        AFRAGS(bufB4)
        const float4* wt = wt4 + 2048;
        NBACC(wt, col0, cA) NBACC(wt, col1, cB)
        float q0 = bcz1[col0], q1 = bcz1[col1];
        LDS4R(cA, q0, col0, usA) LDS4R(cB, q1, col1, usA)
    }
    __syncthreads();
    {   // G3: h = t @ Wm2 + bm2 -> bufB
        AFRAGS(bufA4)
        const float4* wt = wt4 + 2 * 2048;
        NBACC(wt, col0, cA) NBACC(wt, col1, cB)
        float q0 = bbm2[col0], q1 = bbm2[col1];
        LDS4(cA, q0, col0, usB) LDS4(cB, q1, col1, usB)
    }
    __syncthreads();
    {   // G4: ht = h @ Wtm -> sorted rows, bf16
        AFRAGS(bufB4)
        const float4* wt = wt4 + 3 * 2048;
        NBACC(wt, col0, cA) NBACC(wt, col1, cB)
        GBF4S(cA, col0, htb) GBF4S(cB, col1, htb)
    }
    {   // G5: hs = h @ Wsm -> sorted rows, bf16
        AFRAGS(bufB4)
        const float4* wt = wt4 + 4 * 2048;
        NBACC(wt, col0, cA) NBACC(wt, col1, cB)
        GBF4S(cA, col0, hsb) GBF4S(cB, col1, hsb)
    }
    {   // G6: A = h @ Wi1[:128] -> global f32 (original order)
        AFRAGS(bufB4)
        const float4* wt = wt4 + 5 * 2048;
        NBACC(wt, col0, cA) NBACC(wt, col1, cB)
        GF4(cA, 0.f, col0, outA) GF4(cB, 0.f, col1, outA)
    }
    {   // G7: B = h @ Wi1[128:256] + cz2 -> global f32 (in-place over s1;
        // safe: this block read its own seed rows in the prologue)
        AFRAGS(bufB4)
        const float4* wt = wt4 + 6 * 2048;
        NBACC(wt, col0, cA) NBACC(wt, col1, cB)
        float q0 = bcz2[col0], q1 = bcz2[col1];
        GF4(cA, q0, col0, outB) GF4(cB, q1, col1, outB)
    }
}

// ===== Fused bf16-MFMA scores + masked top-2, v16 (best measured 46.3 us) =====
#define STG(buf, q, val) { int r_ = (q) >> 4, c_ = (q) & 15; \
    (buf)[r_ * 16 + (c_ ^ (r_ & 7))] = (val); }

#define KC2(kc, AX, AY) { \
    int co_ = (kc) * 4 + quad; \
    int bo_ = bbase + (co_ ^ brm); \
    s8v b0_ = __builtin_bit_cast(s8v, B[bo_      ]); \
    s8v b1_ = __builtin_bit_cast(s8v, B[bo_ + 256]); \
    s8v b2_ = __builtin_bit_cast(s8v, B[bo_ + 512]); \
    s8v b3_ = __builtin_bit_cast(s8v, B[bo_ + 768]); \
    x0 = __builtin_amdgcn_mfma_f32_16x16x32_bf16(AX, b0_, x0, 0, 0, 0); \
    y0 = __builtin_amdgcn_mfma_f32_16x16x32_bf16(AY, b0_, y0, 0, 0, 0); \
    x1 = __builtin_amdgcn_mfma_f32_16x16x32_bf16(AX, b1_, x1, 0, 0, 0); \
    y1 = __builtin_amdgcn_mfma_f32_16x16x32_bf16(AY, b1_, y1, 0, 0, 0); \
    x2 = __builtin_amdgcn_mfma_f32_16x16x32_bf16(AX, b2_, x2, 0, 0, 0); \
    y2 = __builtin_amdgcn_mfma_f32_16x16x32_bf16(AY, b2_, y2, 0, 0, 0); \
    x3 = __builtin_amdgcn_mfma_f32_16x16x32_bf16(AX, b3_, x3, 0, 0, 0); \
    y3 = __builtin_amdgcn_mfma_f32_16x16x32_bf16(AY, b3_, y3, 0, 0, 0); }

// general merge (boundary tiles): per-element depth mask, desc from LDS
#define RMG(K1, K2, EL, DV) { \
    unsigned pb_ = (__builtin_bit_cast(unsigned, EL) & 0xFFFFC000u) | e_; \
    float sf_ = __builtin_bit_cast(float, (du_ < (DV)) ? pb_ : negp_); \
    K2 = __builtin_amdgcn_fmed3f(K1, K2, sf_); \
    K1 = fmaxf(K1, sf_); }

#define MGEN(nb, XA, YA) { \
    unsigned pk_ = eds[ebase + (nb) * 16 + lane16]; \
    int du_ = (int)(pk_ >> 16); \
    unsigned e_ = pk_ & 0x3FFFu; \
    unsigned negp_ = negbase | e_; \
    RMG(k1x0, k2x0, XA[0], dvx0) RMG(k1x1, k2x1, XA[1], dvx1) \
    RMG(k1x2, k2x2, XA[2], dvx2) RMG(k1x3, k2x3, XA[3], dvx3) \
    RMG(k1y0, k2y0, YA[0], dvy0) RMG(k1y1, k2y1, YA[1], dvy1) \
    RMG(k1y2, k2y2, YA[2], dvy2) RMG(k1y3, k2y3, YA[3], dvy3) }

// fast merge (tile fully valid for all 32 rows of the wave): no mask
#define RMF(K1, K2, EL) { \
    float sf_ = __builtin_bit_cast(float, \
        (__builtin_bit_cast(unsigned, EL) & 0xFFFFC000u) | e_); \
    K2 = __builtin_amdgcn_fmed3f(K1, K2, sf_); \
    K1 = fmaxf(K1, sf_); }

#define MFAST(nb, XA, YA) { \
    unsigned e_ = eds[ebase + (nb) * 16 + lane16] & 0x3FFFu; \
    RMF(k1x0, k2x0, XA[0]) RMF(k1x1, k2x1, XA[1]) \
    RMF(k1x2, k2x2, XA[2]) RMF(k1x3, k2x3, XA[3]) \
    RMF(k1y0, k2y0, YA[0]) RMF(k1y1, k2y1, YA[1]) \
    RMF(k1y2, k2y2, YA[2]) RMF(k1y3, k2y3, YA[3]) }

#define BF1(K1, K2, m) { \
    float o1_ = __shfl_xor(K1, m, 64); \
    float o2_ = __shfl_xor(K2, m, 64); \
    float m2_ = fmaxf(K2, o2_); \
    K2 = __builtin_amdgcn_fmed3f(K1, o1_, m2_); \
    K1 = fmaxf(K1, o1_); }

#define BFALL(m) \
    BF1(k1x0, k2x0, m) BF1(k1x1, k2x1, m) BF1(k1x2, k2x2, m) BF1(k1x3, k2x3, m) \
    BF1(k1y0, k2y0, m) BF1(k1y1, k2y1, m) BF1(k1y2, k2y2, m) BF1(k1y3, k2y3, m)

#define EMIT2(K1, K2, GROW) { \
    size_t o = ((size_t)seg * NN + (GROW)) * 2; \
    pv[o] = K1; pv[o + 1] = K2; }

__global__ __launch_bounds__(256) void k_score_top2_mfma(
        const __hip_bfloat16* __restrict__ htb,
        const __hip_bfloat16* __restrict__ hsb,
        const int* __restrict__ sdep, const int* __restrict__ sidx,
        const int* __restrict__ bofs,
        float* __restrict__ pv) {
    __shared__ float4 Bs4[2][64 * 16];   // 32 KB double buffer (B only)
    __shared__ unsigned eds[12 * 64];    // 3 KB packed (depth<<16)|(0x3FFF-sidx)
    int tid = threadIdx.x;
    int w = tid >> 6;
    int l = tid & 63;
    int lane16 = l & 15;
    int quad = l >> 4;
    int rb = (int)gridDim.x - 1 - (int)blockIdx.x;  // heavy blocks first
    int row0 = rb * 128;
    int seg = blockIdx.y;
    const unsigned negbase = __builtin_bit_cast(unsigned, NEGV) & 0xFFFFC000u;

    // balanced split: ns = ceil(nt/12) active segments (<= 16), ~12 tiles ea.
    int dmax = sdep[row0 + 127];
    int lim = bofs[dmax];
    int nt = (lim + 63) >> 6;               // total tiles, <= 192
    int ns = (nt + 11) / 12;
    if (ns < 1) ns = 1;
    if (seg >= ns) {
        if (tid < 128) {
            int grow = sidx[row0 + tid];
            size_t o = ((size_t)seg * NN + grow) * 2;
            pv[o]     = __builtin_bit_cast(float, negbase | 0x3FFFu);
            pv[o + 1] = __builtin_bit_cast(float, negbase | 0x3FFEu);
        }
        return;
    }
    int t0 = (seg * nt) / ns;
    int t1 = ((seg + 1) * nt) / ns;

    // A fragments: 32 sorted target rows per wave, two 16-row MFMA groups.
    int rbase = row0 + w * 32;
    s8v ax0, ax1, ax2, ax3, ay0, ay1, ay2, ay3;
    {
        const float4* gx = (const float4*)(htb + (size_t)(rbase + lane16) * HD);
        ax0 = __builtin_bit_cast(s8v, gx[quad]);
        ax1 = __builtin_bit_cast(s8v, gx[4 + quad]);
        ax2 = __builtin_bit_cast(s8v, gx[8 + quad]);
        ax3 = __builtin_bit_cast(s8v, gx[12 + quad]);
        const float4* gy = (const float4*)(htb + (size_t)(rbase + 16 + lane16) * HD);
        ay0 = __builtin_bit_cast(s8v, gy[quad]);
        ay1 = __builtin_bit_cast(s8v, gy[4 + quad]);
        ay2 = __builtin_bit_cast(s8v, gy[8 + quad]);
        ay3 = __builtin_bit_cast(s8v, gy[12 + quad]);
    }
    // pack candidate descriptors for the whole segment into LDS (once);
    // consumed only after the first loop-top barrier.
    for (int i = tid; i < (t1 - t0) * 64; i += 256) {
        int p = t0 * 64 + i;
        eds[i] = ((unsigned)sdep[p] << 16) | (0x3FFFu - (unsigned)sidx[p]);
    }
    if (t0 < t1) {   // stage first tile into the parity-matching buffer
        float4* B0 = Bs4[t0 & 1];
        const float4* gb = (const float4*)(hsb + (size_t)(t0 * 64) * HD);
        float4 b0_ = gb[tid], b1_ = gb[tid + 256], b2_ = gb[tid + 512], b3_ = gb[tid + 768];
        STG(B0, tid, b0_) STG(B0, tid + 256, b1_)
        STG(B0, tid + 512, b2_) STG(B0, tid + 768, b3_)
    }

    int bbase = lane16 * 16, brm = lane16 & 7;

    int dvx0 = sdep[rbase + quad * 4 + 0];
    int dvx1 = sdep[rbase + quad * 4 + 1];
    int dvx2 = sdep[rbase + quad * 4 + 2];
    int dvx3 = sdep[rbase + quad * 4 + 3];
    int dvy0 = sdep[rbase + 16 + quad * 4 + 0];
    int dvy1 = sdep[rbase + 16 + quad * 4 + 1];
    int dvy2 = sdep[rbase + 16 + quad * 4 + 2];
    int dvy3 = sdep[rbase + 16 + quad * 4 + 3];
    // wave window: cands < lim_lo valid for EVERY row; >= lim_hi for none.
    int lim_lo = bofs[sdep[rbase]];
    int lim_hi = bofs[sdep[rbase + 31]];

    // defaults: packed NEGV for orig u=0 (k1) and u=1 (k2), lane16==0 only.
    float ki1 = (lane16 == 0) ? __builtin_bit_cast(float, negbase | 0x3FFFu) : -3.4e38f;
    float ki2 = (lane16 == 0) ? __builtin_bit_cast(float, negbase | 0x3FFEu) : -3.4e38f;
    float k1x0 = ki1, k1x1 = ki1, k1x2 = ki1, k1x3 = ki1;
    float k1y0 = ki1, k1y1 = ki1, k1y2 = ki1, k1y3 = ki1;
    float k2x0 = ki2, k2x1 = ki2, k2x2 = ki2, k2x3 = ki2;
    float k2y0 = ki2, k2y1 = ki2, k2y2 = ki2, k2y3 = ki2;

    float4 p0, p1, p2, p3;
    for (int t = t0; t < t1; ++t) {
        int u0 = t * 64;
        int ebase = (t - t0) * 64;
        __syncthreads();
        if (t + 1 < t1) {
            const float4* g = (const float4*)(hsb + (size_t)(u0 + 64) * HD);
            p0 = g[tid]; p1 = g[tid + 256]; p2 = g[tid + 512]; p3 = g[tid + 768];
        }
        if (u0 < lim_hi) {          // wave-uniform: tile matters for >=1 row
            const float4* B = Bs4[t & 1];
            f4v x0 = (f4v){0.f, 0.f, 0.f, 0.f};
            f4v x1 = (f4v){0.f, 0.f, 0.f, 0.f};
            f4v x2 = (f4v){0.f, 0.f, 0.f, 0.f};
            f4v x3 = (f4v){0.f, 0.f, 0.f, 0.f};
            f4v y0 = (f4v){0.f, 0.f, 0.f, 0.f};
            f4v y1 = (f4v){0.f, 0.f, 0.f, 0.f};
            f4v y2 = (f4v){0.f, 0.f, 0.f, 0.f};
            f4v y3 = (f4v){0.f, 0.f, 0.f, 0.f};
            KC2(0, ax0, ay0) KC2(1, ax1, ay1) KC2(2, ax2, ay2) KC2(3, ax3, ay3)
            if (u0 + 64 <= lim_lo) {   // fully valid for all 32 rows
                MFAST(0, x0, y0) MFAST(1, x1, y1)
                MFAST(2, x2, y2) MFAST(3, x3, y3)
            } else {                   // boundary: per-element depth mask
                MGEN(0, x0, y0) MGEN(1, x1, y1)
                MGEN(2, x2, y2) MGEN(3, x3, y3)
            }
        }
        if (t + 1 < t1) {
            float4* Bn = Bs4[(t + 1) & 1];
            STG(Bn, tid, p0) STG(Bn, tid + 256, p1)
            STG(Bn, tid + 512, p2) STG(Bn, tid + 768, p3)
        }
    }

    BFALL(1) BFALL(2) BFALL(4) BFALL(8)

    if (lane16 == 0) {
        int gbse = rbase + quad * 4;
        EMIT2(k1x0, k2x0, sidx[gbse + 0])
        EMIT2(k1x1, k2x1, sidx[gbse + 1])
        EMIT2(k1x2, k2x2, sidx[gbse + 2])
        EMIT2(k1x3, k2x3, sidx[gbse + 3])
        EMIT2(k1y0, k2y0, sidx[gbse + 16])
        EMIT2(k1y1, k2y1, sidx[gbse + 17])
        EMIT2(k1y2, k2y2, sidx[gbse + 18])
        EMIT2(k1y3, k2y3, sidx[gbse + 19])
    }
}

// ONE kernel writes ALL outputs (f32): parallel packed merge (r15-proven).
__global__ __launch_bounds__(256) void k_final(const float* __restrict__ pv,
                                               const int* __restrict__ ntype,
                                               const int* __restrict__ ndepth,
                                               const float* __restrict__ A,
                                               const float* __restrict__ B,
                                               const float* __restrict__ Wi2,
                                               const float* __restrict__ bi2,
                                               float* __restrict__ out) {
    int tid = threadIdx.x;
    int lane = tid & 63;
    int v = blockIdx.x * 4 + (tid >> 6);

    float k1 = -3.4e38f;
    if (lane < 32) {
        k1 = pv[((size_t)(lane >> 1) * NN + v) * 2 + (lane & 1)];
    }
    float k2 = -3.4e38f;
#pragma unroll
    for (int m = 1; m <= 16; m <<= 1) {
        float o1 = __shfl_xor(k1, m, 64);
        float o2 = __shfl_xor(k2, m, 64);
        float m2 = fmaxf(k2, o2);
        k2 = __builtin_amdgcn_fmed3f(k1, o1, m2);
        k1 = fmaxf(k1, o1);
    }
    float K1 = __shfl(k1, 0, 64);
    float K2 = __shfl(k2, 0, 64);
    unsigned b1 = __builtin_bit_cast(unsigned, K1);
    unsigned b2 = __builtin_bit_cast(unsigned, K2);
    int I1 = 0x3FFF - (int)(b1 & 0x3FFFu);
    int I2 = 0x3FFF - (int)(b2 & 0x3FFFu);

    if (lane == 0) {
        int tp = ntype[v];
        bool tv = (tp != 0) && (ndepth[v] > 0) && (K1 > -5.0e8f);  // NEG/2
        out[2 * NN + 2 * v]     = K1;
        out[2 * NN + 2 * v + 1] = K2;
        out[4 * NN + 2 * v]     = (float)I1;
        out[4 * NN + 2 * v + 1] = (float)I2;
        out[6 * NN + 2 * v]     = tv ? 1.f : 0.f;
        out[6 * NN + 2 * v + 1] = (tv && tp == 2) ? 1.f : 0.f;
    }

    int u1 = min(max(I1, 0), NN - 1);
    int u2 = min(max(I2, 0), NN - 1);
    const float2* A2p = (const float2*)A;
    float2 av1 = A2p[(size_t)u1 * 64 + lane];
    float2 av2 = A2p[(size_t)u2 * 64 + lane];
    float2 bv = ((const float2*)B)[(size_t)v * 64 + lane];
    float2 wv = ((const float2*)Wi2)[lane];
    float bias = bi2[0];
    float a1 = fmaf(fmaxf(av1.x + bv.x, 0.f), wv.x,
                    fmaxf(av1.y + bv.y, 0.f) * wv.y);
    float a2 = fmaf(fmaxf(av2.x + bv.x, 0.f), wv.x,
                    fmaxf(av2.y + bv.y, 0.f) * wv.y);
#pragma unroll
    for (int off = 32; off > 0; off >>= 1) {
        a1 += __shfl_down(a1, off);
        a2 += __shfl_down(a2, off);
    }
    if (lane == 0) {
        out[2 * v]     = 1.f / (1.f + expf(-(a1 + bias)));
        out[2 * v + 1] = 1.f / (1.f + expf(-(a2 + bias)));
    }
}

extern "C" void kernel_launch(void* const* d_in, const int* in_sizes, int n_in,
                              void* d_out, int out_size, void* d_ws, size_t ws_size,
                              hipStream_t stream) {
    (void)in_sizes; (void)n_in; (void)out_size; (void)ws_size;
    const float* x   = (const float*)d_in[0];
    const float* z   = (const float*)d_in[1];
    const int* ntype = (const int*)d_in[2];
    const int* ndep  = (const int*)d_in[3];
    const int* eidx  = (const int*)d_in[4];
    const float* W1  = (const float*)d_in[5];
    const float* b1  = (const float*)d_in[6];
    const float* W2  = (const float*)d_in[7];
    const float* b2  = (const float*)d_in[8];
    const float* Wm1 = (const float*)d_in[9];
    const float* bm1 = (const float*)d_in[10];
    const float* Wm2 = (const float*)d_in[11];
    const float* bm2 = (const float*)d_in[12];
    const float* Wsm = (const float*)d_in[13];
    const float* Wtm = (const float*)d_in[14];
    const float* Wi1 = (const float*)d_in[15];
    const float* bi1 = (const float*)d_in[16];
    const float* Wi2 = (const float*)d_in[17];
    const float* bi2 = (const float*)d_in[18];
    float* out = (float*)d_out;

    const int* esrc = eidx;
    const int* edst = eidx + NE;

    // Workspace layout (~24.4 MiB). v18: cnt/dcur sit right after degi so ONE
    // memset zeros degi+cnt (dcur is fully written by k_prefix).
    const size_t S2N = (size_t)SEG * 2 * NN;  // 393216
    float* ws = (float*)d_ws;
    float* pv     = ws;                       // [S2N] f (packed scores)
    int*   pi     = (int*)(pv + S2N);         // [S2N] i (spacer)
    int*   degi   = pi + S2N;                 // [NN]   (memset)
    int*   cnt    = degi + NN;                // [1024] padded depth counts
    int*   dcur   = cnt + 1024;               // [1024] padded depth cursors
    float* inv    = (float*)(dcur + 1024);    // [NN]
    float* agg2   = inv + NN;                 // [2NN]
    float* cz1    = agg2 + 2 * NN;            // [128]
    float* cz2    = cz1 + 128;                // [128]
    int*   offs   = (int*)(cz2 + 128);        // [NN+16]
    int*   cursor = offs + NN + 16;           // [NN]
    int*   bofs   = cursor + NN;              // [80]
    int*   sidx   = bofs + 80;                // [NN]
    int*   sdep   = sidx + NN;                // [NN]
    int*   prank  = sdep + NN;                // [NN]
    int*   ebsrc  = prank + NN;               // [NE]
    float* ebwslot= (float*)(ebsrc + NE);     // [NE] (xi lives here)
    float4* xi    = (float4*)ebwslot;         // [NN] packed (x0,x1,inv,0)
    __hip_bfloat16* wt7 = (__hip_bfloat16*)(ebwslot + NE);  // [7*16384] bf16
    size_t F = (size_t)NN * HD;
    float* s0 = (float*)(wt7 + 7 * 16384);    // h1c (bf16) -> {htb_s, hsb_s}
    float* s1 = s0 + F;                       // aggH seed -> B (in-place)
    float* s2 = s1 + F;                       // A
    unsigned short* h1b = (unsigned short*)s0;
    __hip_bfloat16* htb = (__hip_bfloat16*)s0;
    __hip_bfloat16* hsb = htb + F;

    hipMemsetAsync(degi, 0, (NN + 1024) * sizeof(int), stream);
    k_counts_wz<<<NE / 256 + NN / 256 + 56 + 1, 256, 0, stream>>>(
        edst, ndep, W2, Wm1, Wm2, Wtm, Wsm, Wi1, z, bm1, bi1,
        degi, cnt, wt7, cz1, cz2);
    k_prefix<<<1, 1024, 0, stream>>>(degi, cnt, x, inv, agg2, xi, offs, cursor,
                                     bofs, dcur);
    k_bucket_scatter<<<NE / 256 + NN / 256, 256, 0, stream>>>(
        esrc, edst, ndep, cursor, ebsrc, dcur, sidx, sdep, prank);
    k_gl1<<<NN / 32, 256, 0, stream>>>(offs, ebsrc, xi, agg2, W1, b1, inv,
                                       h1b, s1);
    k_ghmlp7<<<NN / 16, 256, 0, stream>>>(offs, ebsrc, inv, h1b, s1, wt7,
                                          b2, cz1, bm2, cz2, prank,
                                          s2, s1, htb, hsb);
    k_score_top2_mfma<<<dim3(NN / 128, SEG), 256, 0, stream>>>(
        htb, hsb, sdep, sidx, bofs, pv);
    k_final<<<NN / 4, 256, 0, stream>>>(pv, ntype, ndep, s2, s1, Wi2, bi2, out);
}